// Round 8
// baseline (527.829 us; speedup 1.0000x reference)
//
#include <hip/hip_runtime.h>
#include <hip/hip_bf16.h>
#include <hip/hip_fp16.h>
#include <stdint.h>

#define D_MODEL 512
#define NH 8
#define DH 64
#define BB 2
#define SS 4096
#define MTOT (BB*SS)   // 8192

typedef __attribute__((ext_vector_type(8))) short bf16x8;
typedef __attribute__((ext_vector_type(4))) short bf16x4;
typedef __attribute__((ext_vector_type(4))) float f32x4;

#if __has_builtin(__builtin_amdgcn_mfma_f32_16x16x16_bf16)
  #define MFMA16(a,b,c) __builtin_amdgcn_mfma_f32_16x16x16_bf16(a,b,c,0,0,0)
#else
  #define MFMA16(a,b,c) __builtin_amdgcn_mfma_f32_16x16x16bf16_1k(a,b,c,0,0,0)
#endif
#define MFMA32(a,b,c) __builtin_amdgcn_mfma_f32_16x16x32_bf16(a,b,c,0,0,0)

#if __has_builtin(__builtin_amdgcn_exp2f)
  #define EXP2F(x) __builtin_amdgcn_exp2f(x)
#else
  #define EXP2F(x) __expf((x) * 0.6931471805599453f)
#endif

// p = exp(s/8 - 8) = exp2(s*0.125*log2e - 8*log2e); 0.125*log2e folded into Q proj,
// -8*log2e folded into the QK MFMA accumulator init.
#define QSCALE 0.18033688011112042f   // 0.125 * log2(e)
#define EXPOFF 11.541560327679939f    // 8 * log2(e)

// round-half-up bf16: max error 0.5 ulp (same as RNE; only tie direction differs)
__device__ __forceinline__ unsigned f2b(float f) {
  return (__float_as_uint(f) + 0x8000u) >> 16;
}
__device__ __forceinline__ unsigned short f2h(float f) {
  return __half_as_ushort(__float2half(f));   // RNE fp16
}
__device__ __forceinline__ float h2f(unsigned short h) {
  return __half2float(__ushort_as_half(h));
}

__device__ __forceinline__ uint4 pack8(float4 a, float4 b) {
  uint4 r;
  r.x = __builtin_amdgcn_perm(__float_as_uint(a.y) + 0x8000u,
                              __float_as_uint(a.x) + 0x8000u, 0x07060302u);
  r.y = __builtin_amdgcn_perm(__float_as_uint(a.w) + 0x8000u,
                              __float_as_uint(a.z) + 0x8000u, 0x07060302u);
  r.z = __builtin_amdgcn_perm(__float_as_uint(b.y) + 0x8000u,
                              __float_as_uint(b.x) + 0x8000u, 0x07060302u);
  r.w = __builtin_amdgcn_perm(__float_as_uint(b.w) + 0x8000u,
                              __float_as_uint(b.z) + 0x8000u, 0x07060302u);
  return r;
}

// ---------------- GEMM: C[m][n] = sum_k A[m][k]*W[n][k] + bias[n] ----------------
// Tile 64m x 128n, grid (4, 128, z). W fp32 cast to bf16 during staging (half-up).
// mode 0: A fp32. z==0: Q*QSCALE -> [((b*NH+h)*SS+s)*DH+dh]
//                 z==1: K        -> same layout
//                 z==2: V^T col-swizzled -> [((b*NH+h)*DH+dh)*SS+perm(s)]
// mode 1: A = (sum of 4 fp16 partial-O slabs) / (sum of 4 l); fp32 outf[m*512+n]
struct GemmArgs {
  const void* A[3];
  const float* W[3];
  const float* bias[3];
  unsigned short* out[3];
  float* outf;
  const unsigned short* Os[4];   // fp16 partial O slabs
  const float* ls[4];            // partial l
  int mode;
};

__global__ __launch_bounds__(256, 4) void gemm_kernel(GemmArgs g) {
  const int z = blockIdx.z;
  const float* __restrict__ bias = g.bias[z];
  unsigned short* __restrict__ out = g.out[z];
  const bool vt = (g.mode == 0) && (z == 2);
  const float osc = (g.mode == 0 && z == 0) ? QSCALE : 1.0f;

  __shared__ __align__(16) unsigned short lA[64][40];
  __shared__ __align__(16) unsigned short lB[128][40];

  const int t = threadIdx.x;
  const int lane = t & 63;
  const int w = t >> 6;
  const int wr = w >> 1, wc = w & 1;     // wave: m = wr*32+[0,32), n = wc*64+[0,64)
  const int lrow = lane & 15, quad = lane >> 4;
  const int m0 = blockIdx.y * 64;
  const int n0 = blockIdx.x * 128;

  f32x4 acc[2][4];
  for (int i = 0; i < 2; i++)
    for (int j = 0; j < 4; j++)
      for (int r = 0; r < 4; r++) acc[i][j][r] = 0.f;

  const int rowA = t >> 2, c8A = (t & 3) * 8;   // 64 rows x 4 chunks

  for (int kk = 0; kk < 512; kk += 32) {
    // ---- stage A (64x32) ----
    if (g.mode == 0) {
      const float* Af = (const float*)g.A[z];
      float4 a0 = *(const float4*)(Af + (size_t)(m0 + rowA) * 512 + kk + c8A);
      float4 a1 = *(const float4*)(Af + (size_t)(m0 + rowA) * 512 + kk + c8A + 4);
      *(uint4*)&lA[rowA][c8A] = pack8(a0, a1);
    } else {
      const int m = m0 + rowA;
      const int k = kk + c8A;
      const int hh = k >> 6;
      const float inv = __builtin_amdgcn_rcpf(
          g.ls[0][(size_t)m * NH + hh] + g.ls[1][(size_t)m * NH + hh] +
          g.ls[2][(size_t)m * NH + hh] + g.ls[3][(size_t)m * NH + hh]);
      float sum[8] = {0.f, 0.f, 0.f, 0.f, 0.f, 0.f, 0.f, 0.f};
#pragma unroll
      for (int s = 0; s < 4; s++) {
        uint4 hv = *(const uint4*)(g.Os[s] + (size_t)m * 512 + k);
        const unsigned short* he = (const unsigned short*)&hv;
#pragma unroll
        for (int e = 0; e < 8; e++) sum[e] += h2f(he[e]);
      }
      float4 s0 = make_float4(sum[0] * inv, sum[1] * inv, sum[2] * inv, sum[3] * inv);
      float4 s1 = make_float4(sum[4] * inv, sum[5] * inv, sum[6] * inv, sum[7] * inv);
      *(uint4*)&lA[rowA][c8A] = pack8(s0, s1);
    }
    // ---- stage B/W (128x32) ----
#pragma unroll
    for (int i = 0; i < 2; i++) {
      int id = t + i * 256;
      int row = id >> 2;
      int c8 = (id & 3) * 8;
      const float* Wf = g.W[z];
      float4 w0 = *(const float4*)(Wf + (size_t)(n0 + row) * 512 + kk + c8);
      float4 w1 = *(const float4*)(Wf + (size_t)(n0 + row) * 512 + kk + c8 + 4);
      *(uint4*)&lB[row][c8] = pack8(w0, w1);
    }
    __syncthreads();
    bf16x8 af[2], bfr[4];
#pragma unroll
    for (int mt = 0; mt < 2; mt++) af[mt] = *(const bf16x8*)&lA[wr * 32 + mt * 16 + lrow][quad * 8];
#pragma unroll
    for (int nt = 0; nt < 4; nt++) bfr[nt] = *(const bf16x8*)&lB[wc * 64 + nt * 16 + lrow][quad * 8];
#pragma unroll
    for (int mt = 0; mt < 2; mt++)
#pragma unroll
      for (int nt = 0; nt < 4; nt++)
        acc[mt][nt] = MFMA32(af[mt], bfr[nt], acc[mt][nt]);
    __syncthreads();
  }

  float bv[4];
#pragma unroll
  for (int nt = 0; nt < 4; nt++) bv[nt] = bias[n0 + wc * 64 + nt * 16 + lrow];

#pragma unroll
  for (int mt = 0; mt < 2; mt++) {
#pragma unroll
    for (int nt = 0; nt < 4; nt++) {
      const int n = n0 + wc * 64 + nt * 16 + lrow;
      const int mB = m0 + wr * 32 + mt * 16 + quad * 4;   // r=0 row
      float val[4];
#pragma unroll
      for (int r = 0; r < 4; r++) val[r] = (acc[mt][nt][r] + bv[nt]) * osc;

      if (g.mode == 1) {
#pragma unroll
        for (int r = 0; r < 4; r++) g.outf[(size_t)(mB + r) * 512 + n] = val[r];
      } else if (vt) {
        // V^T within-32-group swizzle: s=4a+r -> c = (s&~31)+(a&4)+((a&3)<<3)+r
        const int bb = mB >> 12, s = mB & 4095;
        const int a = s >> 2;
        const int c0 = (s & ~31) + (a & 4) + ((a & 3) << 3);
        const int hh = n >> 6, dh = n & 63;
        ushort4 pk = make_ushort4((unsigned short)f2b(val[0]), (unsigned short)f2b(val[1]),
                                  (unsigned short)f2b(val[2]), (unsigned short)f2b(val[3]));
        *(ushort4*)(out + (((size_t)bb * NH + hh) * DH + dh) * SS + c0) = pk;
      } else {
        const int bb = mB >> 12;
        const int hh = n >> 6, dh = n & 63;
#pragma unroll
        for (int r = 0; r < 4; r++) {
          const int s = (mB + r) & 4095;
          out[((((size_t)bb * NH + hh) * SS + s) << 6) + dh] = (unsigned short)f2b(val[r]);
        }
      }
    }
  }
}

// ---------------- flash attention, S^T formulation, j-split x4 ----------------
// grid (128, NH, BB): blockIdx.x = jq*32 + qtile. 256 thr (4 waves), 32 Q-rows/wave,
// each block covers 16 j-tiles (a quarter of the sequence) -> 2048 blocks.
// Unnormalized fp16 partial O + fp32 partial l per quarter slab; combined exactly
// in the out-GEMM (fixed-max softmax => partials add).
struct AttnArgs {
  const unsigned short* Qh;
  const unsigned short* Kh;
  const unsigned short* Vt;
  unsigned short* Op[4];
  float* lp[4];
};

__global__ __launch_bounds__(256, 6) void attn_kernel(AttnArgs a) {
  __shared__ __align__(16) unsigned short lK[2][64][72];

  const int t = threadIdx.x;
  const int lane = t & 63;
  const int w = t >> 6;
  const int lrow = lane & 15, quad = lane >> 4;
  const int h = blockIdx.y, b = blockIdx.z;
  const int qtile = blockIdx.x & 31, jq = blockIdx.x >> 5;
  const size_t kb = ((size_t)b * NH + h) * SS * DH;   // Q,K: [s][dh]
  const size_t vb = ((size_t)b * NH + h) * DH * SS;   // V^T: [dh][s'] swizzled
  const int qrow0 = qtile * 128 + w * 32;
  unsigned short* __restrict__ Op = a.Op[jq];
  float* __restrict__ lp = a.lp[jq];
  const int jt0 = jq * 16, jt1 = jt0 + 16;

  bf16x8 qf[2][2];
#pragma unroll
  for (int ti = 0; ti < 2; ti++) {
    const unsigned short* qp = a.Qh + kb + (size_t)(qrow0 + ti * 16 + lrow) * DH + quad * 8;
    qf[ti][0] = *(const bf16x8*)qp;
    qf[ti][1] = *(const bf16x8*)(qp + 32);
  }

  bf16x4 ones;
#pragma unroll
  for (int i = 0; i < 4; i++) ones[i] = (short)0x3F80;

  f32x4 o[2][4], lac[2];
#pragma unroll
  for (int ti = 0; ti < 2; ti++) {
    for (int nt = 0; nt < 4; nt++)
      for (int r = 0; r < 4; r++) o[ti][nt][r] = 0.f;
    for (int r = 0; r < 4; r++) lac[ti][r] = 0.f;
  }

  const unsigned short* __restrict__ Kg = a.Kh + kb;
  const unsigned short* __restrict__ Vp = a.Vt + vb + (size_t)lrow * SS + quad * 8;

  const int r0 = t >> 3, r1 = (t + 256) >> 3;      // staging rows
  const int cs = (t & 7) * 8;                      // staging col

  // stage first tile (jt0 even -> buffer parity starts at 0)
  uint4 kreg0 = *(const uint4*)(Kg + (size_t)(jt0 * 64 + r0) * DH + cs);
  uint4 kreg1 = *(const uint4*)(Kg + (size_t)(jt0 * 64 + r1) * DH + cs);
  *(uint4*)&lK[0][r0][cs] = kreg0;
  *(uint4*)&lK[0][r1][cs] = kreg1;

  for (int jt = jt0; jt < jt1; jt++) {
    const int jb = jt * 64;
    __syncthreads();   // lK[jt&1] ready for all waves
    {
      const int nb = (jt + 1 < jt1 ? jt + 1 : jt) * 64;
      kreg0 = *(const uint4*)(Kg + (size_t)(nb + r0) * DH + cs);
      kreg1 = *(const uint4*)(Kg + (size_t)(nb + r1) * DH + cs);
    }

    // S^T = K*Q^T per 16-j group, acc init = -EXPOFF; p = exp2(s); pack bf16x4
    bf16x4 pf[4][2];
#pragma unroll
    for (int ntj = 0; ntj < 4; ntj++) {
      bf16x8 k0 = *(const bf16x8*)&lK[jt & 1][ntj * 16 + lrow][quad * 8];
      bf16x8 k1 = *(const bf16x8*)&lK[jt & 1][ntj * 16 + lrow][32 + quad * 8];
#pragma unroll
      for (int ti = 0; ti < 2; ti++) {
        f32x4 s;
        for (int r = 0; r < 4; r++) s[r] = -EXPOFF;
        s = MFMA32(k0, qf[ti][0], s);
        s = MFMA32(k1, qf[ti][1], s);
        unsigned u0 = __float_as_uint(EXP2F(s[0])) + 0x8000u;
        unsigned u1 = __float_as_uint(EXP2F(s[1])) + 0x8000u;
        unsigned u2 = __float_as_uint(EXP2F(s[2])) + 0x8000u;
        unsigned u3 = __float_as_uint(EXP2F(s[3])) + 0x8000u;
        uint2 pp;
        pp.x = __builtin_amdgcn_perm(u1, u0, 0x07060302u);
        pp.y = __builtin_amdgcn_perm(u3, u2, 0x07060302u);
        pf[ntj][ti] = __builtin_bit_cast(bf16x4, pp);
      }
    }

    // l += 1 * P^T
#pragma unroll
    for (int ks = 0; ks < 4; ks++)
#pragma unroll
      for (int ti = 0; ti < 2; ti++)
        lac[ti] = MFMA16(ones, pf[ks][ti], lac[ti]);

    // O^T += V^T * P^T  (V b128 = two MFMA16 A-frags via the store swizzle)
#pragma unroll
    for (int nt = 0; nt < 4; nt++) {
#pragma unroll
      for (int half = 0; half < 2; half++) {
        bf16x8 vv = *(const bf16x8*)(Vp + (size_t)(nt * 16) * SS + jb + half * 32);
        bf16x4 v0 = __builtin_shufflevector(vv, vv, 0, 1, 2, 3);
        bf16x4 v1 = __builtin_shufflevector(vv, vv, 4, 5, 6, 7);
#pragma unroll
        for (int ti = 0; ti < 2; ti++)
          o[ti][nt] = MFMA16(v0, pf[half * 2 + 0][ti], o[ti][nt]);
#pragma unroll
        for (int ti = 0; ti < 2; ti++)
          o[ti][nt] = MFMA16(v1, pf[half * 2 + 1][ti], o[ti][nt]);
      }
    }

    *(uint4*)&lK[(jt + 1) & 1][r0][cs] = kreg0;
    *(uint4*)&lK[(jt + 1) & 1][r1][cs] = kreg1;
  }

  // epilogue: write unnormalized fp16 partial O and fp32 partial l
#pragma unroll
  for (int ti = 0; ti < 2; ti++) {
    const int si = qrow0 + ti * 16 + lrow;
    unsigned short* dst = Op + ((size_t)(b * SS + si)) * D_MODEL + h * DH;
#pragma unroll
    for (int nt = 0; nt < 4; nt++) {
      ushort4 pk = make_ushort4(f2h(o[ti][nt][0]), f2h(o[ti][nt][1]),
                                f2h(o[ti][nt][2]), f2h(o[ti][nt][3]));
      *(ushort4*)(dst + nt * 16 + quad * 4) = pk;
    }
    if (quad == 0)
      lp[(size_t)(b * SS + si) * NH + h] = lac[ti][0];
  }
}

// ---------------- launch ----------------
extern "C" void kernel_launch(void* const* d_in, const int* in_sizes, int n_in,
                              void* d_out, int out_size, void* d_ws, size_t ws_size,
                              hipStream_t stream) {
  const float* q  = (const float*)d_in[0];
  const float* k  = (const float*)d_in[1];
  const float* v  = (const float*)d_in[2];
  const float* Wq = (const float*)d_in[3];
  const float* bq = (const float*)d_in[4];
  const float* Wk = (const float*)d_in[5];
  const float* bk = (const float*)d_in[6];
  const float* Wv = (const float*)d_in[7];
  const float* bv = (const float*)d_in[8];
  const float* Wo = (const float*)d_in[9];
  const float* bo = (const float*)d_in[10];

  const size_t NX = (size_t)MTOT * D_MODEL;     // 4,194,304

  char* p = (char*)d_ws;
  unsigned short* Qh  = (unsigned short*)p; p += NX * 2;
  unsigned short* Kh  = (unsigned short*)p; p += NX * 2;
  unsigned short* Vtg = (unsigned short*)p; p += NX * 2;
  unsigned short* Os[4];
  float* ls[4];
  for (int i = 0; i < 4; i++) { Os[i] = (unsigned short*)p; p += NX * 2; }
  for (int i = 0; i < 4; i++) { ls[i] = (float*)p; p += (size_t)MTOT * NH * 4; }

  GemmArgs pa;
  pa.A[0] = q; pa.A[1] = k; pa.A[2] = v;
  pa.W[0] = Wq; pa.W[1] = Wk; pa.W[2] = Wv;
  pa.bias[0] = bq; pa.bias[1] = bk; pa.bias[2] = bv;
  pa.out[0] = Qh; pa.out[1] = Kh; pa.out[2] = Vtg;
  pa.outf = nullptr;
  for (int i = 0; i < 4; i++) { pa.Os[i] = nullptr; pa.ls[i] = nullptr; }
  pa.mode = 0;
  gemm_kernel<<<dim3(4, 128, 3), 256, 0, stream>>>(pa);

  AttnArgs aa;
  aa.Qh = Qh; aa.Kh = Kh; aa.Vt = Vtg;
  for (int i = 0; i < 4; i++) { aa.Op[i] = Os[i]; aa.lp[i] = ls[i]; }
  attn_kernel<<<dim3(128, NH, BB), 256, 0, stream>>>(aa);

  GemmArgs oa;
  oa.A[0] = nullptr; oa.A[1] = nullptr; oa.A[2] = nullptr;
  oa.W[0] = Wo; oa.W[1] = Wo; oa.W[2] = Wo;
  oa.bias[0] = bo; oa.bias[1] = bo; oa.bias[2] = bo;
  oa.out[0] = nullptr; oa.out[1] = nullptr; oa.out[2] = nullptr;
  oa.outf = (float*)d_out;
  for (int i = 0; i < 4; i++) { oa.Os[i] = Os[i]; oa.ls[i] = ls[i]; }
  oa.mode = 1;
  gemm_kernel<<<dim3(4, 128, 1), 256, 0, stream>>>(oa);
}

// Round 10
// 323.828 us; speedup vs baseline: 1.6300x; 1.6300x over previous
//
#include <hip/hip_runtime.h>
#include <hip/hip_bf16.h>
#include <hip/hip_fp16.h>
#include <stdint.h>

#define D_MODEL 512
#define NH 8
#define DH 64
#define BB 2
#define SS 4096
#define MTOT (BB*SS)   // 8192

typedef __attribute__((ext_vector_type(8))) short bf16x8;
typedef __attribute__((ext_vector_type(4))) short bf16x4;
typedef __attribute__((ext_vector_type(4))) float f32x4;

#if __has_builtin(__builtin_amdgcn_mfma_f32_16x16x16_bf16)
  #define MFMA16(a,b,c) __builtin_amdgcn_mfma_f32_16x16x16_bf16(a,b,c,0,0,0)
#else
  #define MFMA16(a,b,c) __builtin_amdgcn_mfma_f32_16x16x16bf16_1k(a,b,c,0,0,0)
#endif
#define MFMA32(a,b,c) __builtin_amdgcn_mfma_f32_16x16x32_bf16(a,b,c,0,0,0)

#if __has_builtin(__builtin_amdgcn_exp2f)
  #define EXP2F(x) __builtin_amdgcn_exp2f(x)
#else
  #define EXP2F(x) __expf((x) * 0.6931471805599453f)
#endif

// p = exp(s/8 - 8) = exp2(s*0.125*log2e - 8*log2e); 0.125*log2e folded into Q proj,
// -8*log2e folded into the QK MFMA accumulator init.
#define QSCALE 0.18033688011112042f   // 0.125 * log2(e)
#define EXPOFF 11.541560327679939f    // 8 * log2(e)

// round-half-up bf16: max error 0.5 ulp (same as RNE; only tie direction differs)
__device__ __forceinline__ unsigned f2b(float f) {
  return (__float_as_uint(f) + 0x8000u) >> 16;
}
__device__ __forceinline__ unsigned short f2h(float f) {
  return __half_as_ushort(__float2half(f));   // RNE fp16
}
__device__ __forceinline__ float h2f(unsigned short h) {
  return __half2float(__ushort_as_half(h));
}

__device__ __forceinline__ uint4 pack8(float4 a, float4 b) {
  uint4 r;
  r.x = __builtin_amdgcn_perm(__float_as_uint(a.y) + 0x8000u,
                              __float_as_uint(a.x) + 0x8000u, 0x07060302u);
  r.y = __builtin_amdgcn_perm(__float_as_uint(a.w) + 0x8000u,
                              __float_as_uint(a.z) + 0x8000u, 0x07060302u);
  r.z = __builtin_amdgcn_perm(__float_as_uint(b.y) + 0x8000u,
                              __float_as_uint(b.x) + 0x8000u, 0x07060302u);
  r.w = __builtin_amdgcn_perm(__float_as_uint(b.w) + 0x8000u,
                              __float_as_uint(b.z) + 0x8000u, 0x07060302u);
  return r;
}

// ---------------- GEMM: C[m][n] = sum_k A[m][k]*W[n][k] + bias[n] ----------------
// Tile 64m x 128n, grid (4, 128, z). W fp32 cast to bf16 during staging (half-up).
// mode 0: A fp32. z==0: Q*QSCALE -> [((b*NH+h)*SS+s)*DH+dh]
//                 z==1: K        -> same layout
//                 z==2: V^T col-swizzled -> [((b*NH+h)*DH+dh)*SS+perm(s)]
// mode 1: A = (sum of 4 fp16 partial-O slabs) / (sum of 4 l); fp32 outf[m*512+n]
struct GemmArgs {
  const void* A[3];
  const float* W[3];
  const float* bias[3];
  unsigned short* out[3];
  float* outf;
  const unsigned short* Os[4];   // fp16 partial O slabs
  const float* ls[4];            // partial l
  int mode;
};

__global__ __launch_bounds__(256, 4) void gemm_kernel(GemmArgs g) {
  const int z = blockIdx.z;
  const float* __restrict__ bias = g.bias[z];
  unsigned short* __restrict__ out = g.out[z];
  const bool vt = (g.mode == 0) && (z == 2);
  const float osc = (g.mode == 0 && z == 0) ? QSCALE : 1.0f;

  __shared__ __align__(16) unsigned short lA[64][40];
  __shared__ __align__(16) unsigned short lB[128][40];

  const int t = threadIdx.x;
  const int lane = t & 63;
  const int w = t >> 6;
  const int wr = w >> 1, wc = w & 1;     // wave: m = wr*32+[0,32), n = wc*64+[0,64)
  const int lrow = lane & 15, quad = lane >> 4;
  const int m0 = blockIdx.y * 64;
  const int n0 = blockIdx.x * 128;

  f32x4 acc[2][4];
  for (int i = 0; i < 2; i++)
    for (int j = 0; j < 4; j++)
      for (int r = 0; r < 4; r++) acc[i][j][r] = 0.f;

  const int rowA = t >> 2, c8A = (t & 3) * 8;   // 64 rows x 4 chunks

  for (int kk = 0; kk < 512; kk += 32) {
    // ---- stage A (64x32) ----
    if (g.mode == 0) {
      const float* Af = (const float*)g.A[z];
      float4 a0 = *(const float4*)(Af + (size_t)(m0 + rowA) * 512 + kk + c8A);
      float4 a1 = *(const float4*)(Af + (size_t)(m0 + rowA) * 512 + kk + c8A + 4);
      *(uint4*)&lA[rowA][c8A] = pack8(a0, a1);
    } else {
      const int m = m0 + rowA;
      const int k = kk + c8A;
      const int hh = k >> 6;
      const float inv = __builtin_amdgcn_rcpf(
          g.ls[0][(size_t)m * NH + hh] + g.ls[1][(size_t)m * NH + hh] +
          g.ls[2][(size_t)m * NH + hh] + g.ls[3][(size_t)m * NH + hh]);
      float sum[8] = {0.f, 0.f, 0.f, 0.f, 0.f, 0.f, 0.f, 0.f};
#pragma unroll
      for (int s = 0; s < 4; s++) {
        uint4 hv = *(const uint4*)(g.Os[s] + (size_t)m * 512 + k);
        const unsigned short* he = (const unsigned short*)&hv;
#pragma unroll
        for (int e = 0; e < 8; e++) sum[e] += h2f(he[e]);
      }
      float4 s0 = make_float4(sum[0] * inv, sum[1] * inv, sum[2] * inv, sum[3] * inv);
      float4 s1 = make_float4(sum[4] * inv, sum[5] * inv, sum[6] * inv, sum[7] * inv);
      *(uint4*)&lA[rowA][c8A] = pack8(s0, s1);
    }
    // ---- stage B/W (128x32) ----
#pragma unroll
    for (int i = 0; i < 2; i++) {
      int id = t + i * 256;
      int row = id >> 2;
      int c8 = (id & 3) * 8;
      const float* Wf = g.W[z];
      float4 w0 = *(const float4*)(Wf + (size_t)(n0 + row) * 512 + kk + c8);
      float4 w1 = *(const float4*)(Wf + (size_t)(n0 + row) * 512 + kk + c8 + 4);
      *(uint4*)&lB[row][c8] = pack8(w0, w1);
    }
    __syncthreads();
    bf16x8 af[2], bfr[4];
#pragma unroll
    for (int mt = 0; mt < 2; mt++) af[mt] = *(const bf16x8*)&lA[wr * 32 + mt * 16 + lrow][quad * 8];
#pragma unroll
    for (int nt = 0; nt < 4; nt++) bfr[nt] = *(const bf16x8*)&lB[wc * 64 + nt * 16 + lrow][quad * 8];
#pragma unroll
    for (int mt = 0; mt < 2; mt++)
#pragma unroll
      for (int nt = 0; nt < 4; nt++)
        acc[mt][nt] = MFMA32(af[mt], bfr[nt], acc[mt][nt]);
    __syncthreads();
  }

  float bv[4];
#pragma unroll
  for (int nt = 0; nt < 4; nt++) bv[nt] = bias[n0 + wc * 64 + nt * 16 + lrow];

#pragma unroll
  for (int mt = 0; mt < 2; mt++) {
#pragma unroll
    for (int nt = 0; nt < 4; nt++) {
      const int n = n0 + wc * 64 + nt * 16 + lrow;
      const int mB = m0 + wr * 32 + mt * 16 + quad * 4;   // r=0 row
      float val[4];
#pragma unroll
      for (int r = 0; r < 4; r++) val[r] = (acc[mt][nt][r] + bv[nt]) * osc;

      if (g.mode == 1) {
#pragma unroll
        for (int r = 0; r < 4; r++) g.outf[(size_t)(mB + r) * 512 + n] = val[r];
      } else if (vt) {
        // V^T within-32-group swizzle: s=4a+r -> c = (s&~31)+(a&4)+((a&3)<<3)+r
        const int bb = mB >> 12, s = mB & 4095;
        const int a = s >> 2;
        const int c0 = (s & ~31) + (a & 4) + ((a & 3) << 3);
        const int hh = n >> 6, dh = n & 63;
        ushort4 pk = make_ushort4((unsigned short)f2b(val[0]), (unsigned short)f2b(val[1]),
                                  (unsigned short)f2b(val[2]), (unsigned short)f2b(val[3]));
        *(ushort4*)(out + (((size_t)bb * NH + hh) * DH + dh) * SS + c0) = pk;
      } else {
        const int bb = mB >> 12;
        const int hh = n >> 6, dh = n & 63;
#pragma unroll
        for (int r = 0; r < 4; r++) {
          const int s = (mB + r) & 4095;
          out[((((size_t)bb * NH + hh) * SS + s) << 6) + dh] = (unsigned short)f2b(val[r]);
        }
      }
    }
  }
}

// ---------------- flash attention, S^T formulation, j-split x4 ----------------
// grid (128, NH, BB): blockIdx.x = jq*32 + qtile. 256 thr (4 waves), 32 Q-rows/wave,
// each block covers 16 j-tiles (a quarter of the sequence) -> 2048 blocks.
// K staged via CANONICAL 2-barrier single-buffer LDS (sync; write; sync; compute)
// with register prefetch between the barriers — the R9 single-barrier double-buffer
// raced on graph replay (post-timing divergence). V read direct from global
// (swizzled layout -> b128 = two MFMA16 A-frags). P^T stays in registers.
// Unnormalized fp16 partial O + fp32 partial l per quarter slab; combined exactly
// in the out-GEMM (fixed-max softmax => partials add).
// NOTE: no min-waves hint — R8's (256,6) forced VGPR=40 -> accumulator spills ->
// 1.5 GB HBM scratch traffic. Live set needs ~80-96 VGPRs.
struct AttnArgs {
  const unsigned short* Qh;
  const unsigned short* Kh;
  const unsigned short* Vt;
  unsigned short* Op[4];
  float* lp[4];
};

__global__ __launch_bounds__(256) void attn_kernel(AttnArgs a) {
  __shared__ __align__(16) unsigned short lK[64][72];

  const int t = threadIdx.x;
  const int lane = t & 63;
  const int w = t >> 6;
  const int lrow = lane & 15, quad = lane >> 4;
  const int h = blockIdx.y, b = blockIdx.z;
  const int qtile = blockIdx.x & 31, jq = blockIdx.x >> 5;
  const size_t kb = ((size_t)b * NH + h) * SS * DH;   // Q,K: [s][dh]
  const size_t vb = ((size_t)b * NH + h) * DH * SS;   // V^T: [dh][s'] swizzled
  const int qrow0 = qtile * 128 + w * 32;
  unsigned short* __restrict__ Op = a.Op[jq];
  float* __restrict__ lp = a.lp[jq];
  const int jt0 = jq * 16, jt1 = jt0 + 16;

  bf16x8 qf[2][2];
#pragma unroll
  for (int ti = 0; ti < 2; ti++) {
    const unsigned short* qp = a.Qh + kb + (size_t)(qrow0 + ti * 16 + lrow) * DH + quad * 8;
    qf[ti][0] = *(const bf16x8*)qp;
    qf[ti][1] = *(const bf16x8*)(qp + 32);
  }

  bf16x4 ones;
#pragma unroll
  for (int i = 0; i < 4; i++) ones[i] = (short)0x3F80;

  f32x4 o[2][4], lac[2];
#pragma unroll
  for (int ti = 0; ti < 2; ti++) {
    for (int nt = 0; nt < 4; nt++)
      for (int r = 0; r < 4; r++) o[ti][nt][r] = 0.f;
    for (int r = 0; r < 4; r++) lac[ti][r] = 0.f;
  }

  const unsigned short* __restrict__ Kg = a.Kh + kb;
  const unsigned short* __restrict__ Vp = a.Vt + vb + (size_t)lrow * SS + quad * 8;

  const int r0 = t >> 3, r1 = (t + 256) >> 3;      // staging rows (0..31, 32..63)
  const int cs = (t & 7) * 8;                      // staging col

  // preload tile jt0 into registers
  uint4 kreg0 = *(const uint4*)(Kg + (size_t)(jt0 * 64 + r0) * DH + cs);
  uint4 kreg1 = *(const uint4*)(Kg + (size_t)(jt0 * 64 + r1) * DH + cs);

  for (int jt = jt0; jt < jt1; jt++) {
    const int jb = jt * 64;
    __syncthreads();   // all waves done READING lK (previous iteration)
    *(uint4*)&lK[r0][cs] = kreg0;
    *(uint4*)&lK[r1][cs] = kreg1;
    {
      const int nb = (jt + 1 < jt1 ? jt + 1 : jt) * 64;
      kreg0 = *(const uint4*)(Kg + (size_t)(nb + r0) * DH + cs);
      kreg1 = *(const uint4*)(Kg + (size_t)(nb + r1) * DH + cs);
    }
    __syncthreads();   // tile jt visible to all waves

    // S^T = K*Q^T per 16-j group, acc init = -EXPOFF; p = exp2(s); pack bf16x4
    bf16x4 pf[4][2];
#pragma unroll
    for (int ntj = 0; ntj < 4; ntj++) {
      bf16x8 k0 = *(const bf16x8*)&lK[ntj * 16 + lrow][quad * 8];
      bf16x8 k1 = *(const bf16x8*)&lK[ntj * 16 + lrow][32 + quad * 8];
#pragma unroll
      for (int ti = 0; ti < 2; ti++) {
        f32x4 s;
        for (int r = 0; r < 4; r++) s[r] = -EXPOFF;
        s = MFMA32(k0, qf[ti][0], s);
        s = MFMA32(k1, qf[ti][1], s);
        unsigned u0 = __float_as_uint(EXP2F(s[0])) + 0x8000u;
        unsigned u1 = __float_as_uint(EXP2F(s[1])) + 0x8000u;
        unsigned u2 = __float_as_uint(EXP2F(s[2])) + 0x8000u;
        unsigned u3 = __float_as_uint(EXP2F(s[3])) + 0x8000u;
        uint2 pp;
        pp.x = __builtin_amdgcn_perm(u1, u0, 0x07060302u);
        pp.y = __builtin_amdgcn_perm(u3, u2, 0x07060302u);
        pf[ntj][ti] = __builtin_bit_cast(bf16x4, pp);
      }
    }

    // l += 1 * P^T
#pragma unroll
    for (int ks = 0; ks < 4; ks++)
#pragma unroll
      for (int ti = 0; ti < 2; ti++)
        lac[ti] = MFMA16(ones, pf[ks][ti], lac[ti]);

    // O^T += V^T * P^T  (V b128 = two MFMA16 A-frags via the store swizzle)
#pragma unroll
    for (int nt = 0; nt < 4; nt++) {
#pragma unroll
      for (int half = 0; half < 2; half++) {
        bf16x8 vv = *(const bf16x8*)(Vp + (size_t)(nt * 16) * SS + jb + half * 32);
        bf16x4 v0 = __builtin_shufflevector(vv, vv, 0, 1, 2, 3);
        bf16x4 v1 = __builtin_shufflevector(vv, vv, 4, 5, 6, 7);
#pragma unroll
        for (int ti = 0; ti < 2; ti++)
          o[ti][nt] = MFMA16(v0, pf[half * 2 + 0][ti], o[ti][nt]);
#pragma unroll
        for (int ti = 0; ti < 2; ti++)
          o[ti][nt] = MFMA16(v1, pf[half * 2 + 1][ti], o[ti][nt]);
      }
    }
  }

  // epilogue: write unnormalized fp16 partial O and fp32 partial l
#pragma unroll
  for (int ti = 0; ti < 2; ti++) {
    const int si = qrow0 + ti * 16 + lrow;
    unsigned short* dst = Op + ((size_t)(b * SS + si)) * D_MODEL + h * DH;
#pragma unroll
    for (int nt = 0; nt < 4; nt++) {
      ushort4 pk = make_ushort4(f2h(o[ti][nt][0]), f2h(o[ti][nt][1]),
                                f2h(o[ti][nt][2]), f2h(o[ti][nt][3]));
      *(ushort4*)(dst + nt * 16 + quad * 4) = pk;
    }
    if (quad == 0)
      lp[(size_t)(b * SS + si) * NH + h] = lac[ti][0];
  }
}

// ---------------- launch ----------------
extern "C" void kernel_launch(void* const* d_in, const int* in_sizes, int n_in,
                              void* d_out, int out_size, void* d_ws, size_t ws_size,
                              hipStream_t stream) {
  const float* q  = (const float*)d_in[0];
  const float* k  = (const float*)d_in[1];
  const float* v  = (const float*)d_in[2];
  const float* Wq = (const float*)d_in[3];
  const float* bq = (const float*)d_in[4];
  const float* Wk = (const float*)d_in[5];
  const float* bk = (const float*)d_in[6];
  const float* Wv = (const float*)d_in[7];
  const float* bv = (const float*)d_in[8];
  const float* Wo = (const float*)d_in[9];
  const float* bo = (const float*)d_in[10];

  const size_t NX = (size_t)MTOT * D_MODEL;     // 4,194,304

  char* p = (char*)d_ws;
  unsigned short* Qh  = (unsigned short*)p; p += NX * 2;
  unsigned short* Kh  = (unsigned short*)p; p += NX * 2;
  unsigned short* Vtg = (unsigned short*)p; p += NX * 2;
  unsigned short* Os[4];
  float* ls[4];
  for (int i = 0; i < 4; i++) { Os[i] = (unsigned short*)p; p += NX * 2; }
  for (int i = 0; i < 4; i++) { ls[i] = (float*)p; p += (size_t)MTOT * NH * 4; }

  GemmArgs pa;
  pa.A[0] = q; pa.A[1] = k; pa.A[2] = v;
  pa.W[0] = Wq; pa.W[1] = Wk; pa.W[2] = Wv;
  pa.bias[0] = bq; pa.bias[1] = bk; pa.bias[2] = bv;
  pa.out[0] = Qh; pa.out[1] = Kh; pa.out[2] = Vtg;
  pa.outf = nullptr;
  for (int i = 0; i < 4; i++) { pa.Os[i] = nullptr; pa.ls[i] = nullptr; }
  pa.mode = 0;
  gemm_kernel<<<dim3(4, 128, 3), 256, 0, stream>>>(pa);

  AttnArgs aa;
  aa.Qh = Qh; aa.Kh = Kh; aa.Vt = Vtg;
  for (int i = 0; i < 4; i++) { aa.Op[i] = Os[i]; aa.lp[i] = ls[i]; }
  attn_kernel<<<dim3(128, NH, BB), 256, 0, stream>>>(aa);

  GemmArgs oa;
  oa.A[0] = nullptr; oa.A[1] = nullptr; oa.A[2] = nullptr;
  oa.W[0] = Wo; oa.W[1] = Wo; oa.W[2] = Wo;
  oa.bias[0] = bo; oa.bias[1] = bo; oa.bias[2] = bo;
  oa.out[0] = nullptr; oa.out[1] = nullptr; oa.out[2] = nullptr;
  oa.outf = (float*)d_out;
  for (int i = 0; i < 4; i++) { oa.Os[i] = Os[i]; oa.ls[i] = ls[i]; }
  oa.mode = 1;
  gemm_kernel<<<dim3(4, 128, 1), 256, 0, stream>>>(oa);
}

// Round 11
// 291.156 us; speedup vs baseline: 1.8129x; 1.1122x over previous
//
#include <hip/hip_runtime.h>
#include <hip/hip_bf16.h>
#include <hip/hip_fp16.h>
#include <stdint.h>

#define D_MODEL 512
#define NH 8
#define DH 64
#define BB 2
#define SS 4096
#define MTOT (BB*SS)   // 8192

typedef __attribute__((ext_vector_type(8))) short bf16x8;
typedef __attribute__((ext_vector_type(4))) short bf16x4;
typedef __attribute__((ext_vector_type(4))) float f32x4;

#if __has_builtin(__builtin_amdgcn_mfma_f32_16x16x16_bf16)
  #define MFMA16(a,b,c) __builtin_amdgcn_mfma_f32_16x16x16_bf16(a,b,c,0,0,0)
#else
  #define MFMA16(a,b,c) __builtin_amdgcn_mfma_f32_16x16x16bf16_1k(a,b,c,0,0,0)
#endif
#define MFMA32(a,b,c) __builtin_amdgcn_mfma_f32_16x16x32_bf16(a,b,c,0,0,0)

#if __has_builtin(__builtin_amdgcn_exp2f)
  #define EXP2F(x) __builtin_amdgcn_exp2f(x)
#else
  #define EXP2F(x) __expf((x) * 0.6931471805599453f)
#endif

// p = exp(s/8 - 8) = exp2(s*0.125*log2e - 8*log2e); 0.125*log2e folded into Q proj,
// -8*log2e folded into the QK MFMA accumulator init.
#define QSCALE 0.18033688011112042f   // 0.125 * log2(e)
#define EXPOFF 11.541560327679939f    // 8 * log2(e)

// round-half-up bf16: max error 0.5 ulp (same as RNE; only tie direction differs)
__device__ __forceinline__ unsigned f2b(float f) {
  return (__float_as_uint(f) + 0x8000u) >> 16;
}
__device__ __forceinline__ unsigned short f2h(float f) {
  return __half_as_ushort(__float2half(f));   // RNE fp16
}
__device__ __forceinline__ float h2f(unsigned short h) {
  return __half2float(__ushort_as_half(h));
}

__device__ __forceinline__ unsigned packpair(float lo, float hi) {
  return __builtin_amdgcn_perm(__float_as_uint(hi) + 0x8000u,
                               __float_as_uint(lo) + 0x8000u, 0x07060302u);
}

// ---------------- prep: cast fp32 -> bf16 (q,k,v, 4 weights) ----------------
// Un-folded from GEMM staging: R2-vs-R3 evidence shows separate memory-bound cast
// beats per-kk conversion VALU inside the GEMM inner loop.
struct PrepArgs {
  const float* src[7];
  unsigned short* dst[7];
  int n[7];
};

__global__ __launch_bounds__(256) void prep_kernel(PrepArgs a) {
  const int tgt = blockIdx.y;
  const int i = (blockIdx.x * 256 + threadIdx.x) * 4;
  if (i >= a.n[tgt]) return;
  const float4 f = *(const float4*)(a.src[tgt] + i);
  uint2 o;
  o.x = packpair(f.x, f.y);
  o.y = packpair(f.z, f.w);
  *(uint2*)(a.dst[tgt] + i) = o;
}

// ---------------- GEMM: C[m][n] = sum_k A[m][k]*W[n][k] + bias[n] ----------------
// Tile 64m x 128n, grid (4, 128, z). A and W are PRE-CAST bf16 (pure copy staging).
// mode 0: z==0: Q*QSCALE -> [((b*NH+h)*SS+s)*DH+dh]
//         z==1: K        -> same layout
//         z==2: V^T col-swizzled -> [((b*NH+h)*DH+dh)*SS+perm(s)]
// mode 1: A = (sum of 4 fp16 partial-O slabs) / (sum of 4 l); fp32 outf[m*512+n]
struct GemmArgs {
  const unsigned short* A[3];
  const unsigned short* W[3];
  const float* bias[3];
  unsigned short* out[3];
  float* outf;
  const unsigned short* Os[4];   // fp16 partial O slabs
  const float* ls[4];            // partial l
  int mode;
};

__global__ __launch_bounds__(256, 4) void gemm_kernel(GemmArgs g) {
  const int z = blockIdx.z;
  const float* __restrict__ bias = g.bias[z];
  unsigned short* __restrict__ out = g.out[z];
  const bool vt = (g.mode == 0) && (z == 2);
  const float osc = (g.mode == 0 && z == 0) ? QSCALE : 1.0f;

  __shared__ __align__(16) unsigned short lA[64][40];
  __shared__ __align__(16) unsigned short lB[128][40];

  const int t = threadIdx.x;
  const int lane = t & 63;
  const int w = t >> 6;
  const int wr = w >> 1, wc = w & 1;     // wave: m = wr*32+[0,32), n = wc*64+[0,64)
  const int lrow = lane & 15, quad = lane >> 4;
  const int m0 = blockIdx.y * 64;
  const int n0 = blockIdx.x * 128;

  f32x4 acc[2][4];
  for (int i = 0; i < 2; i++)
    for (int j = 0; j < 4; j++)
      for (int r = 0; r < 4; r++) acc[i][j][r] = 0.f;

  const int rowA = t >> 2, c8A = (t & 3) * 8;   // 64 rows x 4 chunks

  for (int kk = 0; kk < 512; kk += 32) {
    // ---- stage A (64x32) ----
    if (g.mode == 0) {
      *(uint4*)&lA[rowA][c8A] =
          *(const uint4*)(g.A[z] + (size_t)(m0 + rowA) * 512 + kk + c8A);
    } else {
      const int m = m0 + rowA;
      const int k = kk + c8A;
      const int hh = k >> 6;
      const float inv = __builtin_amdgcn_rcpf(
          g.ls[0][(size_t)m * NH + hh] + g.ls[1][(size_t)m * NH + hh] +
          g.ls[2][(size_t)m * NH + hh] + g.ls[3][(size_t)m * NH + hh]);
      float sum[8] = {0.f, 0.f, 0.f, 0.f, 0.f, 0.f, 0.f, 0.f};
#pragma unroll
      for (int s = 0; s < 4; s++) {
        uint4 hv = *(const uint4*)(g.Os[s] + (size_t)m * 512 + k);
        const unsigned short* he = (const unsigned short*)&hv;
#pragma unroll
        for (int e = 0; e < 8; e++) sum[e] += h2f(he[e]);
      }
      uint4 pk;
      pk.x = packpair(sum[0] * inv, sum[1] * inv);
      pk.y = packpair(sum[2] * inv, sum[3] * inv);
      pk.z = packpair(sum[4] * inv, sum[5] * inv);
      pk.w = packpair(sum[6] * inv, sum[7] * inv);
      *(uint4*)&lA[rowA][c8A] = pk;
    }
    // ---- stage B/W (128x32), pure copy ----
#pragma unroll
    for (int i = 0; i < 2; i++) {
      int id = t + i * 256;
      int row = id >> 2;
      int c8 = (id & 3) * 8;
      *(uint4*)&lB[row][c8] =
          *(const uint4*)(g.W[z] + (size_t)(n0 + row) * 512 + kk + c8);
    }
    __syncthreads();
    bf16x8 af[2], bfr[4];
#pragma unroll
    for (int mt = 0; mt < 2; mt++) af[mt] = *(const bf16x8*)&lA[wr * 32 + mt * 16 + lrow][quad * 8];
#pragma unroll
    for (int nt = 0; nt < 4; nt++) bfr[nt] = *(const bf16x8*)&lB[wc * 64 + nt * 16 + lrow][quad * 8];
#pragma unroll
    for (int mt = 0; mt < 2; mt++)
#pragma unroll
      for (int nt = 0; nt < 4; nt++)
        acc[mt][nt] = MFMA32(af[mt], bfr[nt], acc[mt][nt]);
    __syncthreads();
  }

  float bv[4];
#pragma unroll
  for (int nt = 0; nt < 4; nt++) bv[nt] = bias[n0 + wc * 64 + nt * 16 + lrow];

#pragma unroll
  for (int mt = 0; mt < 2; mt++) {
#pragma unroll
    for (int nt = 0; nt < 4; nt++) {
      const int n = n0 + wc * 64 + nt * 16 + lrow;
      const int mB = m0 + wr * 32 + mt * 16 + quad * 4;   // r=0 row
      float val[4];
#pragma unroll
      for (int r = 0; r < 4; r++) val[r] = (acc[mt][nt][r] + bv[nt]) * osc;

      if (g.mode == 1) {
#pragma unroll
        for (int r = 0; r < 4; r++) g.outf[(size_t)(mB + r) * 512 + n] = val[r];
      } else if (vt) {
        // V^T within-32-group swizzle: s=4a+r -> c = (s&~31)+(a&4)+((a&3)<<3)+r
        const int bb = mB >> 12, s = mB & 4095;
        const int a = s >> 2;
        const int c0 = (s & ~31) + (a & 4) + ((a & 3) << 3);
        const int hh = n >> 6, dh = n & 63;
        ushort4 pk = make_ushort4((unsigned short)f2b(val[0]), (unsigned short)f2b(val[1]),
                                  (unsigned short)f2b(val[2]), (unsigned short)f2b(val[3]));
        *(ushort4*)(out + (((size_t)bb * NH + hh) * DH + dh) * SS + c0) = pk;
      } else {
        const int bb = mB >> 12;
        const int hh = n >> 6, dh = n & 63;
#pragma unroll
        for (int r = 0; r < 4; r++) {
          const int s = (mB + r) & 4095;
          out[((((size_t)bb * NH + hh) * SS + s) << 6) + dh] = (unsigned short)f2b(val[r]);
        }
      }
    }
  }
}

// ---------------- flash attention, S^T formulation, j-split x4 ----------------
// grid (64, NH, BB): blockIdx.x = jq*16 + qtile. 256 thr (4 waves), 64 Q-rows/WAVE
// (256 rows/block), 16 j-tiles per block -> 1024 blocks. K AND V staged in LDS
// (V shared by 4 waves: 4x L2 cut), canonical 2-barrier + register prefetch
// (R9's 1-barrier dbuf raced on replay). P^T stays in registers (S^T C-layout ==
// K=16 B-operand). Unnormalized fp16 partial O + fp32 partial l per quarter slab;
// combined exactly in the out-GEMM (fixed-max softmax => partials add).
// NOTE: no min-waves occupancy hint — R8's (256,6) forced spills (1.5 GB scratch).
struct AttnArgs {
  const unsigned short* Qh;
  const unsigned short* Kh;
  const unsigned short* Vt;
  unsigned short* Op[4];
  float* lp[4];
};

__global__ __launch_bounds__(256) void attn_kernel(AttnArgs a) {
  __shared__ __align__(16) unsigned short lK[64][72];
  __shared__ __align__(16) unsigned short lV[64][72];

  const int t = threadIdx.x;
  const int lane = t & 63;
  const int w = t >> 6;
  const int lrow = lane & 15, quad = lane >> 4;
  const int h = blockIdx.y, b = blockIdx.z;
  const int qtile = blockIdx.x & 15, jq = blockIdx.x >> 4;
  const size_t kb = ((size_t)b * NH + h) * SS * DH;   // Q,K: [s][dh]
  const size_t vb = ((size_t)b * NH + h) * DH * SS;   // V^T: [dh][s'] swizzled
  const int qrow0 = qtile * 256 + w * 64;
  unsigned short* __restrict__ Op = a.Op[jq];
  float* __restrict__ lp = a.lp[jq];
  const int jt0 = jq * 16, jt1 = jt0 + 16;

  // Q as B-operand frags for 4 m-tiles (64 rows): reused across all 16 jt
  bf16x8 qf[4][2];
#pragma unroll
  for (int ti = 0; ti < 4; ti++) {
    const unsigned short* qp = a.Qh + kb + (size_t)(qrow0 + ti * 16 + lrow) * DH + quad * 8;
    qf[ti][0] = *(const bf16x8*)qp;
    qf[ti][1] = *(const bf16x8*)(qp + 32);
  }

  bf16x4 ones;
#pragma unroll
  for (int i = 0; i < 4; i++) ones[i] = (short)0x3F80;

  f32x4 o[4][4], lac[4];
#pragma unroll
  for (int ti = 0; ti < 4; ti++) {
    for (int nt = 0; nt < 4; nt++)
      for (int r = 0; r < 4; r++) o[ti][nt][r] = 0.f;
    for (int r = 0; r < 4; r++) lac[ti][r] = 0.f;
  }

  const unsigned short* __restrict__ Kg = a.Kh + kb;
  const unsigned short* __restrict__ Vg = a.Vt + vb;

  const int rk0 = t >> 3, rk1 = (t + 256) >> 3;    // K staging rows
  const int ck = (t & 7) * 8;                      // K staging col
  const int rv = t >> 2;                           // V staging row (d)
  const int cv = (t & 3) * 16;                     // V staging col (s')

  // preload tile jt0 into registers
  uint4 kreg0 = *(const uint4*)(Kg + (size_t)(jt0 * 64 + rk0) * DH + ck);
  uint4 kreg1 = *(const uint4*)(Kg + (size_t)(jt0 * 64 + rk1) * DH + ck);
  uint4 vreg0 = *(const uint4*)(Vg + (size_t)rv * SS + jt0 * 64 + cv);
  uint4 vreg1 = *(const uint4*)(Vg + (size_t)rv * SS + jt0 * 64 + cv + 8);

  for (int jt = jt0; jt < jt1; jt++) {
    __syncthreads();   // all waves done READING lK/lV (previous iteration)
    *(uint4*)&lK[rk0][ck] = kreg0;
    *(uint4*)&lK[rk1][ck] = kreg1;
    *(uint4*)&lV[rv][cv] = vreg0;
    *(uint4*)&lV[rv][cv + 8] = vreg1;
    {
      const int nb = (jt + 1 < jt1 ? jt + 1 : jt) * 64;
      kreg0 = *(const uint4*)(Kg + (size_t)(nb + rk0) * DH + ck);
      kreg1 = *(const uint4*)(Kg + (size_t)(nb + rk1) * DH + ck);
      vreg0 = *(const uint4*)(Vg + (size_t)rv * SS + nb + cv);
      vreg1 = *(const uint4*)(Vg + (size_t)rv * SS + nb + cv + 8);
    }
    __syncthreads();   // tile jt visible to all waves

#pragma unroll
    for (int half = 0; half < 2; half++) {
      // S^T = K*Q^T for 2x16 j-rows; acc init -EXPOFF; p = exp2(s); pack bf16x4
      bf16x4 pf[2][4];
#pragma unroll
      for (int u = 0; u < 2; u++) {
        const int ntj = half * 2 + u;
        bf16x8 k0 = *(const bf16x8*)&lK[ntj * 16 + lrow][quad * 8];
        bf16x8 k1 = *(const bf16x8*)&lK[ntj * 16 + lrow][32 + quad * 8];
#pragma unroll
        for (int ti = 0; ti < 4; ti++) {
          f32x4 s;
          for (int r = 0; r < 4; r++) s[r] = -EXPOFF;
          s = MFMA32(k0, qf[ti][0], s);
          s = MFMA32(k1, qf[ti][1], s);
          uint2 pp;
          pp.x = packpair(EXP2F(s[0]), EXP2F(s[1]));
          pp.y = packpair(EXP2F(s[2]), EXP2F(s[3]));
          pf[u][ti] = __builtin_bit_cast(bf16x4, pp);
        }
      }

      // l += 1 * P^T
#pragma unroll
      for (int u = 0; u < 2; u++)
#pragma unroll
        for (int ti = 0; ti < 4; ti++)
          lac[ti] = MFMA16(ones, pf[u][ti], lac[ti]);

      // O^T += V^T * P^T  (lV b128 = two MFMA16 A-frags via the store swizzle)
#pragma unroll
      for (int nt = 0; nt < 4; nt++) {
        bf16x8 vv = *(const bf16x8*)&lV[nt * 16 + lrow][half * 32 + quad * 8];
        bf16x4 v0 = __builtin_shufflevector(vv, vv, 0, 1, 2, 3);
        bf16x4 v1 = __builtin_shufflevector(vv, vv, 4, 5, 6, 7);
#pragma unroll
        for (int ti = 0; ti < 4; ti++)
          o[ti][nt] = MFMA16(v0, pf[0][ti], o[ti][nt]);
#pragma unroll
        for (int ti = 0; ti < 4; ti++)
          o[ti][nt] = MFMA16(v1, pf[1][ti], o[ti][nt]);
      }
    }
  }

  // epilogue: write unnormalized fp16 partial O and fp32 partial l
#pragma unroll
  for (int ti = 0; ti < 4; ti++) {
    const int si = qrow0 + ti * 16 + lrow;
    unsigned short* dst = Op + ((size_t)(b * SS + si)) * D_MODEL + h * DH;
#pragma unroll
    for (int nt = 0; nt < 4; nt++) {
      ushort4 pk = make_ushort4(f2h(o[ti][nt][0]), f2h(o[ti][nt][1]),
                                f2h(o[ti][nt][2]), f2h(o[ti][nt][3]));
      *(ushort4*)(dst + nt * 16 + quad * 4) = pk;
    }
    if (quad == 0)
      lp[(size_t)(b * SS + si) * NH + h] = lac[ti][0];
  }
}

// ---------------- launch ----------------
extern "C" void kernel_launch(void* const* d_in, const int* in_sizes, int n_in,
                              void* d_out, int out_size, void* d_ws, size_t ws_size,
                              hipStream_t stream) {
  const float* q  = (const float*)d_in[0];
  const float* k  = (const float*)d_in[1];
  const float* v  = (const float*)d_in[2];
  const float* Wq = (const float*)d_in[3];
  const float* bq = (const float*)d_in[4];
  const float* Wk = (const float*)d_in[5];
  const float* bk = (const float*)d_in[6];
  const float* Wv = (const float*)d_in[7];
  const float* bv = (const float*)d_in[8];
  const float* Wo = (const float*)d_in[9];
  const float* bo = (const float*)d_in[10];

  const size_t NX = (size_t)MTOT * D_MODEL;     // 4,194,304
  const size_t NW = (size_t)D_MODEL * D_MODEL;  // 262,144

  char* p = (char*)d_ws;
  unsigned short* qb  = (unsigned short*)p; p += NX * 2;
  unsigned short* kbf = (unsigned short*)p; p += NX * 2;
  unsigned short* vbf = (unsigned short*)p; p += NX * 2;
  unsigned short* Wqb = (unsigned short*)p; p += NW * 2;
  unsigned short* Wkb = (unsigned short*)p; p += NW * 2;
  unsigned short* Wvb = (unsigned short*)p; p += NW * 2;
  unsigned short* Wob = (unsigned short*)p; p += NW * 2;
  unsigned short* Qh  = (unsigned short*)p; p += NX * 2;
  unsigned short* Kh  = (unsigned short*)p; p += NX * 2;
  unsigned short* Vtg = (unsigned short*)p; p += NX * 2;
  unsigned short* Os[4];
  float* ls[4];
  for (int i = 0; i < 4; i++) { Os[i] = (unsigned short*)p; p += NX * 2; }
  for (int i = 0; i < 4; i++) { ls[i] = (float*)p; p += (size_t)MTOT * NH * 4; }

  PrepArgs pr;
  pr.src[0] = q;  pr.dst[0] = qb;  pr.n[0] = (int)NX;
  pr.src[1] = k;  pr.dst[1] = kbf; pr.n[1] = (int)NX;
  pr.src[2] = v;  pr.dst[2] = vbf; pr.n[2] = (int)NX;
  pr.src[3] = Wq; pr.dst[3] = Wqb; pr.n[3] = (int)NW;
  pr.src[4] = Wk; pr.dst[4] = Wkb; pr.n[4] = (int)NW;
  pr.src[5] = Wv; pr.dst[5] = Wvb; pr.n[5] = (int)NW;
  pr.src[6] = Wo; pr.dst[6] = Wob; pr.n[6] = (int)NW;
  prep_kernel<<<dim3(4096, 7, 1), 256, 0, stream>>>(pr);

  GemmArgs pa;
  pa.A[0] = qb; pa.A[1] = kbf; pa.A[2] = vbf;
  pa.W[0] = Wqb; pa.W[1] = Wkb; pa.W[2] = Wvb;
  pa.bias[0] = bq; pa.bias[1] = bk; pa.bias[2] = bv;
  pa.out[0] = Qh; pa.out[1] = Kh; pa.out[2] = Vtg;
  pa.outf = nullptr;
  for (int i = 0; i < 4; i++) { pa.Os[i] = nullptr; pa.ls[i] = nullptr; }
  pa.mode = 0;
  gemm_kernel<<<dim3(4, 128, 3), 256, 0, stream>>>(pa);

  AttnArgs aa;
  aa.Qh = Qh; aa.Kh = Kh; aa.Vt = Vtg;
  for (int i = 0; i < 4; i++) { aa.Op[i] = Os[i]; aa.lp[i] = ls[i]; }
  attn_kernel<<<dim3(64, NH, BB), 256, 0, stream>>>(aa);

  GemmArgs oa;
  oa.A[0] = nullptr; oa.A[1] = nullptr; oa.A[2] = nullptr;
  oa.W[0] = Wob; oa.W[1] = Wob; oa.W[2] = Wob;
  oa.bias[0] = bo; oa.bias[1] = bo; oa.bias[2] = bo;
  oa.out[0] = nullptr; oa.out[1] = nullptr; oa.out[2] = nullptr;
  oa.outf = (float*)d_out;
  for (int i = 0; i < 4; i++) { oa.Os[i] = Os[i]; oa.ls[i] = ls[i]; }
  oa.mode = 1;
  gemm_kernel<<<dim3(4, 128, 1), 256, 0, stream>>>(oa);
}

// Round 13
// 277.809 us; speedup vs baseline: 1.9000x; 1.0480x over previous
//
#include <hip/hip_runtime.h>
#include <hip/hip_bf16.h>
#include <hip/hip_fp16.h>
#include <stdint.h>

#define D_MODEL 512
#define NH 8
#define DH 64
#define BB 2
#define SS 4096
#define MTOT (BB*SS)   // 8192

typedef __attribute__((ext_vector_type(8))) short bf16x8;
typedef __attribute__((ext_vector_type(4))) short bf16x4;
typedef __attribute__((ext_vector_type(4))) float f32x4;
typedef __fp16 fp16x2 __attribute__((ext_vector_type(2)));

#if __has_builtin(__builtin_amdgcn_mfma_f32_16x16x16_bf16)
  #define MFMA16(a,b,c) __builtin_amdgcn_mfma_f32_16x16x16_bf16(a,b,c,0,0,0)
#else
  #define MFMA16(a,b,c) __builtin_amdgcn_mfma_f32_16x16x16bf16_1k(a,b,c,0,0,0)
#endif
#define MFMA32(a,b,c) __builtin_amdgcn_mfma_f32_16x16x32_bf16(a,b,c,0,0,0)

#if __has_builtin(__builtin_amdgcn_exp2f)
  #define EXP2F(x) __builtin_amdgcn_exp2f(x)
#else
  #define EXP2F(x) __expf((x) * 0.6931471805599453f)
#endif

// p = exp(s/8 - 8) = exp2(s*0.125*log2e - 8*log2e); 0.125*log2e folded into Q proj,
// -8*log2e folded into the QK MFMA accumulator init.
#define QSCALE 0.18033688011112042f   // 0.125 * log2(e)
#define EXPOFF 11.541560327679939f    // 8 * log2(e)

// round-half-up bf16: max error 0.5 ulp (same as RNE; only tie direction differs)
__device__ __forceinline__ unsigned f2b(float f) {
  return (__float_as_uint(f) + 0x8000u) >> 16;
}
__device__ __forceinline__ float h2f(unsigned short h) {
  return __half2float(__ushort_as_half(h));
}
// packed f32x2 -> f16x2 (RTZ), single VALU op, lo=src0
__device__ __forceinline__ unsigned packh2(float lo, float hi) {
  fp16x2 h = __builtin_amdgcn_cvt_pkrtz(lo, hi);
  return __builtin_bit_cast(unsigned, h);
}
__device__ __forceinline__ unsigned packpair(float lo, float hi) {
  return __builtin_amdgcn_perm(__float_as_uint(hi) + 0x8000u,
                               __float_as_uint(lo) + 0x8000u, 0x07060302u);
}

// ---------------- prep: cast fp32 -> bf16 (q,k,v, 4 weights) ----------------
struct PrepArgs {
  const float* src[7];
  unsigned short* dst[7];
  int n[7];
};

__global__ __launch_bounds__(256) void prep_kernel(PrepArgs a) {
  const int tgt = blockIdx.y;
  const int i = (blockIdx.x * 256 + threadIdx.x) * 4;
  if (i >= a.n[tgt]) return;
  const float4 f = *(const float4*)(a.src[tgt] + i);
  uint2 o;
  o.x = packpair(f.x, f.y);
  o.y = packpair(f.z, f.w);
  *(uint2*)(a.dst[tgt] + i) = o;
}

// ---------------- combine: Ao = (sum of 4 fp16 slabs) / (sum of 4 l), bf16 ----
struct CombArgs {
  const unsigned short* Os[4];
  const float* ls[4];
  unsigned short* Ao;
};

__global__ __launch_bounds__(256) void combine_kernel(CombArgs c) {
  const size_t i = ((size_t)blockIdx.x * 256 + threadIdx.x) * 8;   // element idx
  const int m = (int)(i >> 9);
  const int k = (int)(i & 511);
  const int hh = k >> 6;
  const float inv = __builtin_amdgcn_rcpf(
      c.ls[0][(size_t)m * NH + hh] + c.ls[1][(size_t)m * NH + hh] +
      c.ls[2][(size_t)m * NH + hh] + c.ls[3][(size_t)m * NH + hh]);
  float sum[8] = {0.f, 0.f, 0.f, 0.f, 0.f, 0.f, 0.f, 0.f};
#pragma unroll
  for (int s = 0; s < 4; s++) {
    uint4 hv = *(const uint4*)(c.Os[s] + i);
    const unsigned short* he = (const unsigned short*)&hv;
#pragma unroll
    for (int e = 0; e < 8; e++) sum[e] += h2f(he[e]);
  }
  uint4 pk;
  pk.x = packpair(sum[0] * inv, sum[1] * inv);
  pk.y = packpair(sum[2] * inv, sum[3] * inv);
  pk.z = packpair(sum[4] * inv, sum[5] * inv);
  pk.w = packpair(sum[6] * inv, sum[7] * inv);
  *(uint4*)(c.Ao + i) = pk;
}

// ---------------- GEMM: C[m][n] = sum_k A[m][k]*W[n][k] + bias[n] ----------------
// 128x128 tile (R2's proven structure: 16 MFMA32/wave per barrier pair), grid
// (4, 64, z). A and W pre-cast bf16 -> pure uint4 copy staging.
// mode 0: z==0: Q*QSCALE -> [((b*NH+h)*SS+s)*DH+dh]
//         z==1: K        -> same layout
//         z==2: V^T col-swizzled -> [((b*NH+h)*DH+dh)*SS+perm(s)]
// mode 1: A = combined bf16 Ao; fp32 outf[m*512+n]
struct GemmArgs {
  const unsigned short* A[3];
  const unsigned short* W[3];
  const float* bias[3];
  unsigned short* out[3];
  float* outf;
  int mode;
};

__global__ __launch_bounds__(256) void gemm_kernel(GemmArgs g) {
  const int z = blockIdx.z;
  const float* __restrict__ bias = g.bias[z];
  unsigned short* __restrict__ out = g.out[z];
  const bool vt = (g.mode == 0) && (z == 2);
  const float osc = (g.mode == 0 && z == 0) ? QSCALE : 1.0f;

  __shared__ __align__(16) unsigned short lA[128][40];
  __shared__ __align__(16) unsigned short lB[128][40];

  const int t = threadIdx.x;
  const int lane = t & 63;
  const int w = t >> 6;
  const int wr = w >> 1, wc = w & 1;
  const int lrow = lane & 15, quad = lane >> 4;
  const int m0 = blockIdx.y * 128;
  const int n0 = blockIdx.x * 128;

  f32x4 acc[4][4];
  for (int i = 0; i < 4; i++)
    for (int j = 0; j < 4; j++)
      for (int r = 0; r < 4; r++) acc[i][j][r] = 0.f;

  for (int kk = 0; kk < 512; kk += 32) {
#pragma unroll
    for (int i = 0; i < 2; i++) {
      int id = t + i * 256;          // 0..511
      int row = id >> 2;             // 0..127
      int c8 = (id & 3) * 8;         // 0,8,16,24
      *(uint4*)&lA[row][c8] = *(const uint4*)(g.A[z] + (size_t)(m0 + row) * 512 + kk + c8);
      *(uint4*)&lB[row][c8] = *(const uint4*)(g.W[z] + (size_t)(n0 + row) * 512 + kk + c8);
    }
    __syncthreads();
    bf16x8 af[4], bfr[4];
#pragma unroll
    for (int mt = 0; mt < 4; mt++) af[mt] = *(const bf16x8*)&lA[wr * 64 + mt * 16 + lrow][quad * 8];
#pragma unroll
    for (int nt = 0; nt < 4; nt++) bfr[nt] = *(const bf16x8*)&lB[wc * 64 + nt * 16 + lrow][quad * 8];
#pragma unroll
    for (int mt = 0; mt < 4; mt++)
#pragma unroll
      for (int nt = 0; nt < 4; nt++)
        acc[mt][nt] = MFMA32(af[mt], bfr[nt], acc[mt][nt]);
    __syncthreads();
  }

  float bv[4];
#pragma unroll
  for (int nt = 0; nt < 4; nt++) bv[nt] = bias[n0 + wc * 64 + nt * 16 + lrow];

#pragma unroll
  for (int mt = 0; mt < 4; mt++) {
#pragma unroll
    for (int nt = 0; nt < 4; nt++) {
      const int n = n0 + wc * 64 + nt * 16 + lrow;
      const int mB = m0 + wr * 64 + mt * 16 + quad * 4;   // r=0 row
      float val[4];
#pragma unroll
      for (int r = 0; r < 4; r++) val[r] = (acc[mt][nt][r] + bv[nt]) * osc;

      if (g.mode == 1) {
#pragma unroll
        for (int r = 0; r < 4; r++) g.outf[(size_t)(mB + r) * 512 + n] = val[r];
      } else if (vt) {
        // V^T within-32-group swizzle: s=4a+r -> c = (s&~31)+(a&4)+((a&3)<<3)+r
        const int bb = mB >> 12, s = mB & 4095;
        const int a = s >> 2;
        const int c0 = (s & ~31) + (a & 4) + ((a & 3) << 3);
        const int hh = n >> 6, dh = n & 63;
        ushort4 pk = make_ushort4((unsigned short)f2b(val[0]), (unsigned short)f2b(val[1]),
                                  (unsigned short)f2b(val[2]), (unsigned short)f2b(val[3]));
        *(ushort4*)(out + (((size_t)bb * NH + hh) * DH + dh) * SS + c0) = pk;
      } else {
        const int bb = mB >> 12;
        const int hh = n >> 6, dh = n & 63;
#pragma unroll
        for (int r = 0; r < 4; r++) {
          const int s = (mB + r) & 4095;
          out[((((size_t)bb * NH + hh) * SS + s) << 6) + dh] = (unsigned short)f2b(val[r]);
        }
      }
    }
  }
}

// ---------------- flash attention, S^T formulation, j-split x4 ----------------
// grid (64, NH, BB): blockIdx.x = jq*16 + qtile. 256 thr (4 waves), 64 Q-rows/WAVE,
// 16 j-tiles per block -> 1024 blocks. K AND V staged in LDS, canonical 2-barrier +
// register prefetch (R9's 1-barrier dbuf raced on replay). P^T stays in registers
// (S^T C-layout == K=16 B-operand). Unnormalized fp16 partial O + fp32 partial l
// per quarter slab; combined exactly in combine_kernel (fixed-max softmax).
// NOTE: no min-waves occupancy hint — R8's (256,6) forced spills (1.5 GB scratch).
struct AttnArgs {
  const unsigned short* Qh;
  const unsigned short* Kh;
  const unsigned short* Vt;
  unsigned short* Op[4];
  float* lp[4];
};

__global__ __launch_bounds__(256) void attn_kernel(AttnArgs a) {
  __shared__ __align__(16) unsigned short lK[64][72];
  __shared__ __align__(16) unsigned short lV[64][72];

  const int t = threadIdx.x;
  const int lane = t & 63;
  const int w = t >> 6;
  const int lrow = lane & 15, quad = lane >> 4;
  const int h = blockIdx.y, b = blockIdx.z;
  const int qtile = blockIdx.x & 15, jq = blockIdx.x >> 4;
  const size_t kb = ((size_t)b * NH + h) * SS * DH;   // Q,K: [s][dh]
  const size_t vb = ((size_t)b * NH + h) * DH * SS;   // V^T: [dh][s'] swizzled
  const int qrow0 = qtile * 256 + w * 64;
  unsigned short* __restrict__ Op = a.Op[jq];
  float* __restrict__ lp = a.lp[jq];
  const int jt0 = jq * 16, jt1 = jt0 + 16;

  bf16x8 qf[4][2];
#pragma unroll
  for (int ti = 0; ti < 4; ti++) {
    const unsigned short* qp = a.Qh + kb + (size_t)(qrow0 + ti * 16 + lrow) * DH + quad * 8;
    qf[ti][0] = *(const bf16x8*)qp;
    qf[ti][1] = *(const bf16x8*)(qp + 32);
  }

  bf16x4 ones;
#pragma unroll
  for (int i = 0; i < 4; i++) ones[i] = (short)0x3F80;

  f32x4 o[4][4], lac[4];
#pragma unroll
  for (int ti = 0; ti < 4; ti++) {
    for (int nt = 0; nt < 4; nt++)
      for (int r = 0; r < 4; r++) o[ti][nt][r] = 0.f;
    for (int r = 0; r < 4; r++) lac[ti][r] = 0.f;
  }

  const unsigned short* __restrict__ Kg = a.Kh + kb;
  const unsigned short* __restrict__ Vg = a.Vt + vb;

  const int rk0 = t >> 3, rk1 = (t + 256) >> 3;    // K staging rows
  const int ck = (t & 7) * 8;                      // K staging col
  const int rv = t >> 2;                           // V staging row (d)
  const int cv = (t & 3) * 16;                     // V staging col (s')

  uint4 kreg0 = *(const uint4*)(Kg + (size_t)(jt0 * 64 + rk0) * DH + ck);
  uint4 kreg1 = *(const uint4*)(Kg + (size_t)(jt0 * 64 + rk1) * DH + ck);
  uint4 vreg0 = *(const uint4*)(Vg + (size_t)rv * SS + jt0 * 64 + cv);
  uint4 vreg1 = *(const uint4*)(Vg + (size_t)rv * SS + jt0 * 64 + cv + 8);

  for (int jt = jt0; jt < jt1; jt++) {
    __syncthreads();   // all waves done READING lK/lV (previous iteration)
    *(uint4*)&lK[rk0][ck] = kreg0;
    *(uint4*)&lK[rk1][ck] = kreg1;
    *(uint4*)&lV[rv][cv] = vreg0;
    *(uint4*)&lV[rv][cv + 8] = vreg1;
    {
      const int nb = (jt + 1 < jt1 ? jt + 1 : jt) * 64;
      kreg0 = *(const uint4*)(Kg + (size_t)(nb + rk0) * DH + ck);
      kreg1 = *(const uint4*)(Kg + (size_t)(nb + rk1) * DH + ck);
      vreg0 = *(const uint4*)(Vg + (size_t)rv * SS + nb + cv);
      vreg1 = *(const uint4*)(Vg + (size_t)rv * SS + nb + cv + 8);
    }
    __syncthreads();   // tile jt visible to all waves

#pragma unroll
    for (int half = 0; half < 2; half++) {
      bf16x4 pf[2][4];
#pragma unroll
      for (int u = 0; u < 2; u++) {
        const int ntj = half * 2 + u;
        bf16x8 k0 = *(const bf16x8*)&lK[ntj * 16 + lrow][quad * 8];
        bf16x8 k1 = *(const bf16x8*)&lK[ntj * 16 + lrow][32 + quad * 8];
#pragma unroll
        for (int ti = 0; ti < 4; ti++) {
          f32x4 s;
          for (int r = 0; r < 4; r++) s[r] = -EXPOFF;
          s = MFMA32(k0, qf[ti][0], s);
          s = MFMA32(k1, qf[ti][1], s);
          uint2 pp;
          pp.x = packpair(EXP2F(s[0]), EXP2F(s[1]));
          pp.y = packpair(EXP2F(s[2]), EXP2F(s[3]));
          pf[u][ti] = __builtin_bit_cast(bf16x4, pp);
        }
      }

#pragma unroll
      for (int u = 0; u < 2; u++)
#pragma unroll
        for (int ti = 0; ti < 4; ti++)
          lac[ti] = MFMA16(ones, pf[u][ti], lac[ti]);

#pragma unroll
      for (int nt = 0; nt < 4; nt++) {
        bf16x8 vv = *(const bf16x8*)&lV[nt * 16 + lrow][half * 32 + quad * 8];
        bf16x4 v0 = __builtin_shufflevector(vv, vv, 0, 1, 2, 3);
        bf16x4 v1 = __builtin_shufflevector(vv, vv, 4, 5, 6, 7);
#pragma unroll
        for (int ti = 0; ti < 4; ti++)
          o[ti][nt] = MFMA16(v0, pf[0][ti], o[ti][nt]);
#pragma unroll
        for (int ti = 0; ti < 4; ti++)
          o[ti][nt] = MFMA16(v1, pf[1][ti], o[ti][nt]);
      }
    }
  }

  // epilogue: write unnormalized fp16 partial O (pkrtz) and fp32 partial l
#pragma unroll
  for (int ti = 0; ti < 4; ti++) {
    const int si = qrow0 + ti * 16 + lrow;
    unsigned short* dst = Op + ((size_t)(b * SS + si)) * D_MODEL + h * DH;
#pragma unroll
    for (int nt = 0; nt < 4; nt++) {
      uint2 pk;
      pk.x = packh2(o[ti][nt][0], o[ti][nt][1]);
      pk.y = packh2(o[ti][nt][2], o[ti][nt][3]);
      *(uint2*)(dst + nt * 16 + quad * 4) = pk;
    }
    if (quad == 0)
      lp[(size_t)(b * SS + si) * NH + h] = lac[ti][0];
  }
}

// ---------------- launch ----------------
extern "C" void kernel_launch(void* const* d_in, const int* in_sizes, int n_in,
                              void* d_out, int out_size, void* d_ws, size_t ws_size,
                              hipStream_t stream) {
  const float* q  = (const float*)d_in[0];
  const float* k  = (const float*)d_in[1];
  const float* v  = (const float*)d_in[2];
  const float* Wq = (const float*)d_in[3];
  const float* bq = (const float*)d_in[4];
  const float* Wk = (const float*)d_in[5];
  const float* bk = (const float*)d_in[6];
  const float* Wv = (const float*)d_in[7];
  const float* bv = (const float*)d_in[8];
  const float* Wo = (const float*)d_in[9];
  const float* bo = (const float*)d_in[10];

  const size_t NX = (size_t)MTOT * D_MODEL;     // 4,194,304
  const size_t NW = (size_t)D_MODEL * D_MODEL;  // 262,144

  char* p = (char*)d_ws;
  unsigned short* qb  = (unsigned short*)p; p += NX * 2;
  unsigned short* kbf = (unsigned short*)p; p += NX * 2;
  unsigned short* vbf = (unsigned short*)p; p += NX * 2;
  unsigned short* Wqb = (unsigned short*)p; p += NW * 2;
  unsigned short* Wkb = (unsigned short*)p; p += NW * 2;
  unsigned short* Wvb = (unsigned short*)p; p += NW * 2;
  unsigned short* Wob = (unsigned short*)p; p += NW * 2;
  unsigned short* Qh  = (unsigned short*)p; p += NX * 2;
  unsigned short* Kh  = (unsigned short*)p; p += NX * 2;
  unsigned short* Vtg = (unsigned short*)p; p += NX * 2;
  unsigned short* Ao  = (unsigned short*)p; p += NX * 2;
  unsigned short* Os[4];
  float* ls[4];
  for (int i = 0; i < 4; i++) { Os[i] = (unsigned short*)p; p += NX * 2; }
  for (int i = 0; i < 4; i++) { ls[i] = (float*)p; p += (size_t)MTOT * NH * 4; }

  PrepArgs pr;
  pr.src[0] = q;  pr.dst[0] = qb;  pr.n[0] = (int)NX;
  pr.src[1] = k;  pr.dst[1] = kbf; pr.n[1] = (int)NX;
  pr.src[2] = v;  pr.dst[2] = vbf; pr.n[2] = (int)NX;
  pr.src[3] = Wq; pr.dst[3] = Wqb; pr.n[3] = (int)NW;
  pr.src[4] = Wk; pr.dst[4] = Wkb; pr.n[4] = (int)NW;
  pr.src[5] = Wv; pr.dst[5] = Wvb; pr.n[5] = (int)NW;
  pr.src[6] = Wo; pr.dst[6] = Wob; pr.n[6] = (int)NW;
  prep_kernel<<<dim3(4096, 7, 1), 256, 0, stream>>>(pr);

  GemmArgs pa;
  pa.A[0] = qb; pa.A[1] = kbf; pa.A[2] = vbf;
  pa.W[0] = Wqb; pa.W[1] = Wkb; pa.W[2] = Wvb;
  pa.bias[0] = bq; pa.bias[1] = bk; pa.bias[2] = bv;
  pa.out[0] = Qh; pa.out[1] = Kh; pa.out[2] = Vtg;
  pa.outf = nullptr;
  pa.mode = 0;
  gemm_kernel<<<dim3(4, 64, 3), 256, 0, stream>>>(pa);

  AttnArgs aa;
  aa.Qh = Qh; aa.Kh = Kh; aa.Vt = Vtg;
  for (int i = 0; i < 4; i++) { aa.Op[i] = Os[i]; aa.lp[i] = ls[i]; }
  attn_kernel<<<dim3(64, NH, BB), 256, 0, stream>>>(aa);

  CombArgs ca;
  for (int i = 0; i < 4; i++) { ca.Os[i] = Os[i]; ca.ls[i] = ls[i]; }
  ca.Ao = Ao;
  combine_kernel<<<dim3((int)(NX / 8 / 256), 1, 1), 256, 0, stream>>>(ca);

  GemmArgs oa;
  oa.A[0] = Ao; oa.A[1] = Ao; oa.A[2] = Ao;
  oa.W[0] = Wob; oa.W[1] = Wob; oa.W[2] = Wob;
  oa.bias[0] = bo; oa.bias[1] = bo; oa.bias[2] = bo;
  oa.out[0] = nullptr; oa.out[1] = nullptr; oa.out[2] = nullptr;
  oa.outf = (float*)d_out;
  oa.mode = 1;
  gemm_kernel<<<dim3(4, 64, 1), 256, 0, stream>>>(oa);
}

// Round 14
// 275.211 us; speedup vs baseline: 1.9179x; 1.0094x over previous
//
#include <hip/hip_runtime.h>
#include <hip/hip_bf16.h>
#include <hip/hip_fp16.h>
#include <stdint.h>

#define D_MODEL 512
#define NH 8
#define DH 64
#define BB 2
#define SS 4096
#define MTOT (BB*SS)   // 8192

typedef __attribute__((ext_vector_type(8))) short bf16x8;
typedef __attribute__((ext_vector_type(4))) short bf16x4;
typedef __attribute__((ext_vector_type(4))) float f32x4;
typedef __fp16 fp16x2 __attribute__((ext_vector_type(2)));

#if __has_builtin(__builtin_amdgcn_mfma_f32_16x16x16_bf16)
  #define MFMA16(a,b,c) __builtin_amdgcn_mfma_f32_16x16x16_bf16(a,b,c,0,0,0)
#else
  #define MFMA16(a,b,c) __builtin_amdgcn_mfma_f32_16x16x16bf16_1k(a,b,c,0,0,0)
#endif
#define MFMA32(a,b,c) __builtin_amdgcn_mfma_f32_16x16x32_bf16(a,b,c,0,0,0)

#if __has_builtin(__builtin_amdgcn_exp2f)
  #define EXP2F(x) __builtin_amdgcn_exp2f(x)
#else
  #define EXP2F(x) __expf((x) * 0.6931471805599453f)
#endif

// p = exp(s/8 - 8) = exp2(s*0.125*log2e - 8*log2e); 0.125*log2e folded into Q proj,
// -8*log2e folded into the QK MFMA accumulator init.
#define QSCALE 0.18033688011112042f   // 0.125 * log2(e)
#define EXPOFF 11.541560327679939f    // 8 * log2(e)

// round-half-up bf16: max error 0.5 ulp (same as RNE; only tie direction differs)
__device__ __forceinline__ unsigned f2b(float f) {
  return (__float_as_uint(f) + 0x8000u) >> 16;
}
__device__ __forceinline__ float h2f(unsigned short h) {
  return __half2float(__ushort_as_half(h));
}
// packed f32x2 -> f16x2 (RTZ), single VALU op, lo=src0
__device__ __forceinline__ unsigned packh2(float lo, float hi) {
  fp16x2 h = __builtin_amdgcn_cvt_pkrtz(lo, hi);
  return __builtin_bit_cast(unsigned, h);
}
__device__ __forceinline__ unsigned packpair(float lo, float hi) {
  return __builtin_amdgcn_perm(__float_as_uint(hi) + 0x8000u,
                               __float_as_uint(lo) + 0x8000u, 0x07060302u);
}

// ---------------- prep: cast fp32 -> bf16 (q,k,v, 4 weights) ----------------
// Tight 1D grid: blocks-per-slice via cumulative offsets (R13's (4096,7) grid
// launched ~16k immediate-return blocks for the weight slices).
struct PrepArgs {
  const float* src[7];
  unsigned short* dst[7];
  int off[8];   // cumulative block offsets; slice sizes are multiples of 1024
};

__global__ __launch_bounds__(256) void prep_kernel(PrepArgs a) {
  const int bx = blockIdx.x;
  int tgt = 0;
#pragma unroll
  for (int s = 1; s < 7; s++) tgt += (bx >= a.off[s]);
  const int i = ((bx - a.off[tgt]) * 256 + threadIdx.x) * 4;
  const float4 f = *(const float4*)(a.src[tgt] + i);
  uint2 o;
  o.x = packpair(f.x, f.y);
  o.y = packpair(f.z, f.w);
  *(uint2*)(a.dst[tgt] + i) = o;
}

// ---------------- combine: Ao = (sum of 4 fp16 slabs) / (sum of 4 l), bf16 ----
struct CombArgs {
  const unsigned short* Os[4];
  const float* ls[4];
  unsigned short* Ao;
};

__global__ __launch_bounds__(256) void combine_kernel(CombArgs c) {
  const size_t i = ((size_t)blockIdx.x * 256 + threadIdx.x) * 8;   // element idx
  const int m = (int)(i >> 9);
  const int k = (int)(i & 511);
  const int hh = k >> 6;
  const float inv = __builtin_amdgcn_rcpf(
      c.ls[0][(size_t)m * NH + hh] + c.ls[1][(size_t)m * NH + hh] +
      c.ls[2][(size_t)m * NH + hh] + c.ls[3][(size_t)m * NH + hh]);
  float sum[8] = {0.f, 0.f, 0.f, 0.f, 0.f, 0.f, 0.f, 0.f};
#pragma unroll
  for (int s = 0; s < 4; s++) {
    uint4 hv = *(const uint4*)(c.Os[s] + i);
    const unsigned short* he = (const unsigned short*)&hv;
#pragma unroll
    for (int e = 0; e < 8; e++) sum[e] += h2f(he[e]);
  }
  uint4 pk;
  pk.x = packpair(sum[0] * inv, sum[1] * inv);
  pk.y = packpair(sum[2] * inv, sum[3] * inv);
  pk.z = packpair(sum[4] * inv, sum[5] * inv);
  pk.w = packpair(sum[6] * inv, sum[7] * inv);
  *(uint4*)(c.Ao + i) = pk;
}

// ---------------- GEMM: C[m][n] = sum_k A[m][k]*W[n][k] + bias[n] ----------------
// 128x128 tile, grid (4, 64, z). A and W pre-cast bf16 -> pure uint4 copy staging.
// mode 0: z==0: Q*QSCALE -> [((b*NH+h)*SS+s)*DH+dh]
//         z==1: K        -> same layout
//         z==2: V^T col-swizzled -> [((b*NH+h)*DH+dh)*SS+perm(s)]
// mode 1: A = combined bf16 Ao; fp32 outf[m*512+n]
struct GemmArgs {
  const unsigned short* A[3];
  const unsigned short* W[3];
  const float* bias[3];
  unsigned short* out[3];
  float* outf;
  int mode;
};

__global__ __launch_bounds__(256) void gemm_kernel(GemmArgs g) {
  const int z = blockIdx.z;
  const float* __restrict__ bias = g.bias[z];
  unsigned short* __restrict__ out = g.out[z];
  const bool vt = (g.mode == 0) && (z == 2);
  const float osc = (g.mode == 0 && z == 0) ? QSCALE : 1.0f;

  __shared__ __align__(16) unsigned short lA[128][40];
  __shared__ __align__(16) unsigned short lB[128][40];

  const int t = threadIdx.x;
  const int lane = t & 63;
  const int w = t >> 6;
  const int wr = w >> 1, wc = w & 1;
  const int lrow = lane & 15, quad = lane >> 4;
  const int m0 = blockIdx.y * 128;
  const int n0 = blockIdx.x * 128;

  f32x4 acc[4][4];
  for (int i = 0; i < 4; i++)
    for (int j = 0; j < 4; j++)
      for (int r = 0; r < 4; r++) acc[i][j][r] = 0.f;

  for (int kk = 0; kk < 512; kk += 32) {
#pragma unroll
    for (int i = 0; i < 2; i++) {
      int id = t + i * 256;          // 0..511
      int row = id >> 2;             // 0..127
      int c8 = (id & 3) * 8;         // 0,8,16,24
      *(uint4*)&lA[row][c8] = *(const uint4*)(g.A[z] + (size_t)(m0 + row) * 512 + kk + c8);
      *(uint4*)&lB[row][c8] = *(const uint4*)(g.W[z] + (size_t)(n0 + row) * 512 + kk + c8);
    }
    __syncthreads();
    bf16x8 af[4], bfr[4];
#pragma unroll
    for (int mt = 0; mt < 4; mt++) af[mt] = *(const bf16x8*)&lA[wr * 64 + mt * 16 + lrow][quad * 8];
#pragma unroll
    for (int nt = 0; nt < 4; nt++) bfr[nt] = *(const bf16x8*)&lB[wc * 64 + nt * 16 + lrow][quad * 8];
#pragma unroll
    for (int mt = 0; mt < 4; mt++)
#pragma unroll
      for (int nt = 0; nt < 4; nt++)
        acc[mt][nt] = MFMA32(af[mt], bfr[nt], acc[mt][nt]);
    __syncthreads();
  }

  float bv[4];
#pragma unroll
  for (int nt = 0; nt < 4; nt++) bv[nt] = bias[n0 + wc * 64 + nt * 16 + lrow];

#pragma unroll
  for (int mt = 0; mt < 4; mt++) {
#pragma unroll
    for (int nt = 0; nt < 4; nt++) {
      const int n = n0 + wc * 64 + nt * 16 + lrow;
      const int mB = m0 + wr * 64 + mt * 16 + quad * 4;   // r=0 row
      float val[4];
#pragma unroll
      for (int r = 0; r < 4; r++) val[r] = (acc[mt][nt][r] + bv[nt]) * osc;

      if (g.mode == 1) {
#pragma unroll
        for (int r = 0; r < 4; r++) g.outf[(size_t)(mB + r) * 512 + n] = val[r];
      } else if (vt) {
        // V^T within-32-group swizzle: s=4a+r -> c = (s&~31)+(a&4)+((a&3)<<3)+r
        const int bb = mB >> 12, s = mB & 4095;
        const int a = s >> 2;
        const int c0 = (s & ~31) + (a & 4) + ((a & 3) << 3);
        const int hh = n >> 6, dh = n & 63;
        ushort4 pk = make_ushort4((unsigned short)f2b(val[0]), (unsigned short)f2b(val[1]),
                                  (unsigned short)f2b(val[2]), (unsigned short)f2b(val[3]));
        *(ushort4*)(out + (((size_t)bb * NH + hh) * DH + dh) * SS + c0) = pk;
      } else {
        const int bb = mB >> 12;
        const int hh = n >> 6, dh = n & 63;
#pragma unroll
        for (int r = 0; r < 4; r++) {
          const int s = (mB + r) & 4095;
          out[((((size_t)bb * NH + hh) * SS + s) << 6) + dh] = (unsigned short)f2b(val[r]);
        }
      }
    }
  }
}

// ---------------- flash attention, S^T formulation, j-split x4 ----------------
// grid (64, NH, BB): blockIdx.x = jq*16 + qtile. 256 thr (4 waves), 64 Q-rows/WAVE,
// 16 j-tiles per block -> 1024 blocks. K AND V staged in LDS, canonical 2-barrier +
// register prefetch (R9's 1-barrier dbuf raced on replay). P^T stays in registers
// (S^T C-layout == K=16 B-operand). l accumulated in VALU (fp32 sums of exp2
// outputs + end-of-kernel cross-quad shfl) — R13's ones-MFMA l cost 20% of MFMA
// slots and 18 registers. Unnormalized fp16 partial O + fp32 partial l per
// quarter slab; combined exactly in combine_kernel (fixed-max softmax).
// NOTE: no min-waves occupancy hint — R8's (256,6) forced spills (1.5 GB scratch).
struct AttnArgs {
  const unsigned short* Qh;
  const unsigned short* Kh;
  const unsigned short* Vt;
  unsigned short* Op[4];
  float* lp[4];
};

__global__ __launch_bounds__(256) void attn_kernel(AttnArgs a) {
  __shared__ __align__(16) unsigned short lK[64][72];
  __shared__ __align__(16) unsigned short lV[64][72];

  const int t = threadIdx.x;
  const int lane = t & 63;
  const int w = t >> 6;
  const int lrow = lane & 15, quad = lane >> 4;
  const int h = blockIdx.y, b = blockIdx.z;
  const int qtile = blockIdx.x & 15, jq = blockIdx.x >> 4;
  const size_t kb = ((size_t)b * NH + h) * SS * DH;   // Q,K: [s][dh]
  const size_t vb = ((size_t)b * NH + h) * DH * SS;   // V^T: [dh][s'] swizzled
  const int qrow0 = qtile * 256 + w * 64;
  unsigned short* __restrict__ Op = a.Op[jq];
  float* __restrict__ lp = a.lp[jq];
  const int jt0 = jq * 16, jt1 = jt0 + 16;

  bf16x8 qf[4][2];
#pragma unroll
  for (int ti = 0; ti < 4; ti++) {
    const unsigned short* qp = a.Qh + kb + (size_t)(qrow0 + ti * 16 + lrow) * DH + quad * 8;
    qf[ti][0] = *(const bf16x8*)qp;
    qf[ti][1] = *(const bf16x8*)(qp + 32);
  }

  f32x4 o[4][4];
  float lsum[4] = {0.f, 0.f, 0.f, 0.f};
#pragma unroll
  for (int ti = 0; ti < 4; ti++)
    for (int nt = 0; nt < 4; nt++)
      for (int r = 0; r < 4; r++) o[ti][nt][r] = 0.f;

  const unsigned short* __restrict__ Kg = a.Kh + kb;
  const unsigned short* __restrict__ Vg = a.Vt + vb;

  const int rk0 = t >> 3, rk1 = (t + 256) >> 3;    // K staging rows
  const int ck = (t & 7) * 8;                      // K staging col
  const int rv = t >> 2;                           // V staging row (d)
  const int cv = (t & 3) * 16;                     // V staging col (s')

  uint4 kreg0 = *(const uint4*)(Kg + (size_t)(jt0 * 64 + rk0) * DH + ck);
  uint4 kreg1 = *(const uint4*)(Kg + (size_t)(jt0 * 64 + rk1) * DH + ck);
  uint4 vreg0 = *(const uint4*)(Vg + (size_t)rv * SS + jt0 * 64 + cv);
  uint4 vreg1 = *(const uint4*)(Vg + (size_t)rv * SS + jt0 * 64 + cv + 8);

  for (int jt = jt0; jt < jt1; jt++) {
    __syncthreads();   // all waves done READING lK/lV (previous iteration)
    *(uint4*)&lK[rk0][ck] = kreg0;
    *(uint4*)&lK[rk1][ck] = kreg1;
    *(uint4*)&lV[rv][cv] = vreg0;
    *(uint4*)&lV[rv][cv + 8] = vreg1;
    {
      const int nb = (jt + 1 < jt1 ? jt + 1 : jt) * 64;
      kreg0 = *(const uint4*)(Kg + (size_t)(nb + rk0) * DH + ck);
      kreg1 = *(const uint4*)(Kg + (size_t)(nb + rk1) * DH + ck);
      vreg0 = *(const uint4*)(Vg + (size_t)rv * SS + nb + cv);
      vreg1 = *(const uint4*)(Vg + (size_t)rv * SS + nb + cv + 8);
    }
    __syncthreads();   // tile jt visible to all waves

#pragma unroll
    for (int half = 0; half < 2; half++) {
      bf16x4 pf[2][4];
#pragma unroll
      for (int u = 0; u < 2; u++) {
        const int ntj = half * 2 + u;
        bf16x8 k0 = *(const bf16x8*)&lK[ntj * 16 + lrow][quad * 8];
        bf16x8 k1 = *(const bf16x8*)&lK[ntj * 16 + lrow][32 + quad * 8];
#pragma unroll
        for (int ti = 0; ti < 4; ti++) {
          f32x4 s;
          for (int r = 0; r < 4; r++) s[r] = -EXPOFF;
          s = MFMA32(k0, qf[ti][0], s);
          s = MFMA32(k1, qf[ti][1], s);
          const float e0 = EXP2F(s[0]);
          const float e1 = EXP2F(s[1]);
          const float e2 = EXP2F(s[2]);
          const float e3 = EXP2F(s[3]);
          lsum[ti] += (e0 + e1) + (e2 + e3);
          uint2 pp;
          pp.x = packpair(e0, e1);
          pp.y = packpair(e2, e3);
          pf[u][ti] = __builtin_bit_cast(bf16x4, pp);
        }
      }

#pragma unroll
      for (int nt = 0; nt < 4; nt++) {
        bf16x8 vv = *(const bf16x8*)&lV[nt * 16 + lrow][half * 32 + quad * 8];
        bf16x4 v0 = __builtin_shufflevector(vv, vv, 0, 1, 2, 3);
        bf16x4 v1 = __builtin_shufflevector(vv, vv, 4, 5, 6, 7);
#pragma unroll
        for (int ti = 0; ti < 4; ti++)
          o[ti][nt] = MFMA16(v0, pf[0][ti], o[ti][nt]);
#pragma unroll
        for (int ti = 0; ti < 4; ti++)
          o[ti][nt] = MFMA16(v1, pf[1][ti], o[ti][nt]);
      }
    }
  }

  // epilogue: write unnormalized fp16 partial O (pkrtz) and fp32 partial l
  // (cross-quad reduce: row i's p-mass is spread over the 4 quads)
#pragma unroll
  for (int ti = 0; ti < 4; ti++) {
    float l = lsum[ti];
    l += __shfl_xor(l, 16);
    l += __shfl_xor(l, 32);
    const int si = qrow0 + ti * 16 + lrow;
    unsigned short* dst = Op + ((size_t)(b * SS + si)) * D_MODEL + h * DH;
#pragma unroll
    for (int nt = 0; nt < 4; nt++) {
      uint2 pk;
      pk.x = packh2(o[ti][nt][0], o[ti][nt][1]);
      pk.y = packh2(o[ti][nt][2], o[ti][nt][3]);
      *(uint2*)(dst + nt * 16 + quad * 4) = pk;
    }
    if (quad == 0)
      lp[(size_t)(b * SS + si) * NH + h] = l;
  }
}

// ---------------- launch ----------------
extern "C" void kernel_launch(void* const* d_in, const int* in_sizes, int n_in,
                              void* d_out, int out_size, void* d_ws, size_t ws_size,
                              hipStream_t stream) {
  const float* q  = (const float*)d_in[0];
  const float* k  = (const float*)d_in[1];
  const float* v  = (const float*)d_in[2];
  const float* Wq = (const float*)d_in[3];
  const float* bq = (const float*)d_in[4];
  const float* Wk = (const float*)d_in[5];
  const float* bk = (const float*)d_in[6];
  const float* Wv = (const float*)d_in[7];
  const float* bv = (const float*)d_in[8];
  const float* Wo = (const float*)d_in[9];
  const float* bo = (const float*)d_in[10];

  const size_t NX = (size_t)MTOT * D_MODEL;     // 4,194,304
  const size_t NW = (size_t)D_MODEL * D_MODEL;  // 262,144

  char* p = (char*)d_ws;
  unsigned short* qb  = (unsigned short*)p; p += NX * 2;
  unsigned short* kbf = (unsigned short*)p; p += NX * 2;
  unsigned short* vbf = (unsigned short*)p; p += NX * 2;
  unsigned short* Wqb = (unsigned short*)p; p += NW * 2;
  unsigned short* Wkb = (unsigned short*)p; p += NW * 2;
  unsigned short* Wvb = (unsigned short*)p; p += NW * 2;
  unsigned short* Wob = (unsigned short*)p; p += NW * 2;
  unsigned short* Qh  = (unsigned short*)p; p += NX * 2;
  unsigned short* Kh  = (unsigned short*)p; p += NX * 2;
  unsigned short* Vtg = (unsigned short*)p; p += NX * 2;
  unsigned short* Ao  = (unsigned short*)p; p += NX * 2;
  unsigned short* Os[4];
  float* ls[4];
  for (int i = 0; i < 4; i++) { Os[i] = (unsigned short*)p; p += NX * 2; }
  for (int i = 0; i < 4; i++) { ls[i] = (float*)p; p += (size_t)MTOT * NH * 4; }

  PrepArgs pr;
  pr.src[0] = q;  pr.dst[0] = qb;
  pr.src[1] = k;  pr.dst[1] = kbf;
  pr.src[2] = v;  pr.dst[2] = vbf;
  pr.src[3] = Wq; pr.dst[3] = Wqb;
  pr.src[4] = Wk; pr.dst[4] = Wkb;
  pr.src[5] = Wv; pr.dst[5] = Wvb;
  pr.src[6] = Wo; pr.dst[6] = Wob;
  {
    const int nb[7] = {(int)(NX / 1024), (int)(NX / 1024), (int)(NX / 1024),
                       (int)(NW / 1024), (int)(NW / 1024), (int)(NW / 1024),
                       (int)(NW / 1024)};
    int acc = 0;
    for (int i = 0; i < 7; i++) { pr.off[i] = acc; acc += nb[i]; }
    pr.off[7] = acc;
    prep_kernel<<<dim3(acc, 1, 1), 256, 0, stream>>>(pr);
  }

  GemmArgs pa;
  pa.A[0] = qb; pa.A[1] = kbf; pa.A[2] = vbf;
  pa.W[0] = Wqb; pa.W[1] = Wkb; pa.W[2] = Wvb;
  pa.bias[0] = bq; pa.bias[1] = bk; pa.bias[2] = bv;
  pa.out[0] = Qh; pa.out[1] = Kh; pa.out[2] = Vtg;
  pa.outf = nullptr;
  pa.mode = 0;
  gemm_kernel<<<dim3(4, 64, 3), 256, 0, stream>>>(pa);

  AttnArgs aa;
  aa.Qh = Qh; aa.Kh = Kh; aa.Vt = Vtg;
  for (int i = 0; i < 4; i++) { aa.Op[i] = Os[i]; aa.lp[i] = ls[i]; }
  attn_kernel<<<dim3(64, NH, BB), 256, 0, stream>>>(aa);

  CombArgs ca;
  for (int i = 0; i < 4; i++) { ca.Os[i] = Os[i]; ca.ls[i] = ls[i]; }
  ca.Ao = Ao;
  combine_kernel<<<dim3((int)(NX / 8 / 256), 1, 1), 256, 0, stream>>>(ca);

  GemmArgs oa;
  oa.A[0] = Ao; oa.A[1] = Ao; oa.A[2] = Ao;
  oa.W[0] = Wob; oa.W[1] = Wob; oa.W[2] = Wob;
  oa.bias[0] = bo; oa.bias[1] = bo; oa.bias[2] = bo;
  oa.out[0] = nullptr; oa.out[1] = nullptr; oa.out[2] = nullptr;
  oa.outf = (float*)d_out;
  oa.mode = 1;
  gemm_kernel<<<dim3(4, 64, 1), 256, 0, stream>>>(oa);
}